// Round 2
// baseline (445.290 us; speedup 1.0000x reference)
//
#include <hip/hip_runtime.h>
#include <hip/hip_bf16.h>

#define BATCH 4096
#define NTHR 512

typedef __attribute__((ext_vector_type(8))) short bf16x8;
typedef __attribute__((ext_vector_type(4))) float f32x4;
typedef __attribute__((ext_vector_type(4))) short short4v;

// CK-style barrier: drain LDS only, leave global prefetches in flight
#define BAR() asm volatile("s_waitcnt lgkmcnt(0)\n\ts_barrier" ::: "memory")
#define MFMA16(a, b, c) __builtin_amdgcn_mfma_f32_16x16x32_bf16(a, b, c, 0, 0, 0)

// dh-sorted packing: group g (= degree) has cnt(g) units, prefix off1(g)
__host__ __device__ __forceinline__ int off1(int g) { return (g <= 16) ? 17 * g : 16 * g + 16; }
__host__ __device__ __forceinline__ int cntg(int g) { return (g < 16) ? 17 : 16; }
__host__ __device__ __forceinline__ int unitOf(int p) {
    int gp, jp;
    if (p < 272) { gp = p / 17; jp = p - gp * 17; }
    else         { gp = (p >> 4) - 1; jp = p & 15; }
    return gp + 63 * jp;
}
__device__ __forceinline__ short f2bf(float f) {
    __hip_bfloat16 h = __float2bfloat16(f);
    return *reinterpret_cast<short*>(&h);
}
__device__ __forceinline__ float bfrnd(float f) {
    __hip_bfloat16 h = __float2bfloat16(f);
    return __bfloat162float(h);
}

// ---------------- prep6: LDS-staged coalesced packing (512 thr) — unchanged ----------------
__global__ void prep6(const float* __restrict__ W0, const float* __restrict__ b0,
                      const float* __restrict__ W1, const float* __restrict__ b1,
                      const float* __restrict__ W2,
                      short* __restrict__ W1f, short* __restrict__ W2f,
                      short* __restrict__ W0f, float* __restrict__ b1p) {
    __shared__ short ws[16][1024];
    const int b = blockIdx.x, t = threadIdx.x;
    if (b < 72) {
        const bool isW1 = (b < 64);
        const int n = t >> 5;                 // staged slot 0..15
        int u;
        if (isW1) u = unitOf(b * 16 + n);
        else { const int c = b - 64; u = (n & 1) ? (64 + c * 8 + (n >> 1)) : (c * 8 + (n >> 1)); }
        const float* src = isW1 ? (W1 + (long)u * 1024) : (W2 + (long)u * 1024);
        const int c0 = (t & 31) * 4;
#pragma unroll
        for (int j = 0; j < 8; ++j) {
            int c = c0 + j * 128;
            float4 v = *(const float4*)&src[c];
            short4v sv;
            sv[0] = f2bf(v.x); sv[1] = f2bf(v.y); sv[2] = f2bf(v.z); sv[3] = f2bf(v.w);
            *(short4v*)&ws[n][c] = sv;
        }
        __syncthreads();
#pragma unroll 1
        for (int it = 0; it < 8; ++it) {
            int v = t + it * 512;
            if (v < 4032) {
                int g = v >> 6, lane2 = v & 63;
                int nn = lane2 & 15, aq2 = lane2 >> 4;
                bf16x8 pk;
#pragma unroll
                for (int e = 0; e < 8; ++e) {
                    int k = aq2 * 8 + e;
                    pk[e] = (k < cntg(g)) ? ws[nn][g + 63 * k] : (short)0;
                }
                if (isW1) *(bf16x8*)&W1f[(((long)g * 64 + b) * 64 + lane2) * 8] = pk;
                else      *(bf16x8*)&W2f[(((long)g * 8 + (b - 64)) * 64 + lane2) * 8] = pk;
            }
        }
    } else if (b < 88) {
        const int bb = b - 72;
#pragma unroll 1
        for (int j = 0; j < 16; ++j) {
            int q = t + j * 512;
            if (q < 8064) {
                int idx = bb * 8064 + q;
                int g = idx >> 11, rem = idx & 2047;
                int n2 = rem >> 10, kt = (rem >> 9) & 1, lane2 = (rem >> 3) & 63, e = rem & 7;
                int sl = n2 * 16 + (lane2 & 15);
                int kp = kt * 32 + ((lane2 >> 4) << 3) + e;
                float val = 0.f;
                if (sl < cntg(g)) {
                    int u = unitOf(off1(g) + sl);
                    if (kp == 0) val = b0[u];
                    else if (kp - 1 <= g) val = W0[u * 64 + kp - 1];
                }
                W0f[idx] = f2bf(val);
            }
        }
    } else {
        for (int p = t; p < 1024; p += 512) b1p[p] = b1[unitOf(p)];
    }
}

// ---------------- made7b: window scheme, spill-free ----------------
// Identical algorithm to made7; __launch_bounds__(512,1) lifts the VGPR cap 128->256
// (grid=256 blocks on 256 CUs -> 1 block/CU resident regardless, so nothing lost).
// Round-1 regression was pure scratch spill: VGPR demand ~200 vs cap 128.
__global__ __launch_bounds__(NTHR, 1) void made7b(
    const float* __restrict__ uin, const float* __restrict__ b2,
    const float* __restrict__ W0,
    const short* __restrict__ W1f, const short* __restrict__ W2f,
    const short* __restrict__ W0f, const float* __restrict__ b1p,
    float* __restrict__ out) {

    __shared__ __align__(16) short h1w[2][8][16][40];   // [par][slot][m][j], cols 17..31 stay 0
    __shared__ __align__(16) short h2w[2][8][16][40];
    __shared__ __align__(16) short xhist[16][80];       // [m][k']: k'=0 bias 1.0, k'=i+1 -> x_i
    __shared__ __align__(16) float uT[64][16];
    __shared__ __align__(16) float xLs[16][68];
    __shared__ float ldjpart[8][16];

    const int t = threadIdx.x, lane = t & 63, wv = t >> 6;
    const int n = lane & 15, aq = lane >> 4;
    const int rowbase = blockIdx.x * 16;

    {   // zero LDS (K pads must stay 0 forever)
        int* z1 = (int*)&h1w[0][0][0][0];
#pragma unroll 1
        for (int idx = t; idx < 5120; idx += NTHR) z1[idx] = 0;
        int* z2 = (int*)&h2w[0][0][0][0];
#pragma unroll 1
        for (int idx = t; idx < 5120; idx += NTHR) z2[idx] = 0;
        int* z3 = (int*)&xhist[0][0];
#pragma unroll 1
        for (int idx = t; idx < 640; idx += NTHR) z3[idx] = 0;
    }
    if (t < 256) {
        int r = t >> 4, c0 = (t & 15) * 4;
        float4 v = *(const float4*)&uin[(long)(rowbase + r) * 64 + c0];
        uT[c0 + 0][r] = v.x; uT[c0 + 1][r] = v.y; uT[c0 + 2][r] = v.z; uT[c0 + 3][r] = v.w;
    }

    // private tile range: tiles covering groups [gA, gB]
    const int gA = (wv == 0) ? 0 : 8 * wv - 1;
    const int gB = (8 * wv + 6 > 62) ? 62 : 8 * wv + 6;
    const int TLO = off1(gA) >> 4;
    const int NT = ((off1(gB) + cntg(gB) - 1) >> 4) - TLO + 1;   // 8 or 9

    f32x4 acc2own[9];
#pragma unroll
    for (int tt = 0; tt < 9; ++tt) {
        float bb = (tt < NT) ? b1p[(TLO + tt) * 16 + n] : 0.f;
        acc2own[tt] = (f32x4){bb, bb, bb, bb};
    }
    f32x4 zacc;
    {
        int pc = wv * 16 + n;               // packed z col; orig r = (pc>>1)+64*(pc&1)
        float bz = b2[(pc >> 1) + 64 * (pc & 1)];
        zacc = (f32x4){bz, bz, bz, bz};
    }

    // rank-1 coefficients: filled in publisher prologue (only active wave loads them)
    float w0d[8], w0d16[8];

    f32x4 ldjacc = {0.f, 0.f, 0.f, 0.f};
    bf16x8 w1A[9], w1B[9], w2E, w2O, w0fa, w0fb, w0fc;

    BAR();
    if (t < 16) xhist[t][0] = (short)0x3F80;   // bias col = 1.0 (wave 0, same-wave first use)
    float ureg[4];
#pragma unroll
    for (int r = 0; r < 4; ++r) ureg[r] = uT[8 * wv + (n >> 1)][aq * 4 + r];

    // ---- window-boundary catch-up: batch-apply previous window's groups ----
    auto catchup = [&](int w) {
        // zacc: groups 8w-9 .. 8w-2
#pragma unroll
        for (int gk = 0; gk < 8; ++gk) {
            const int g = 8 * w - 9 + gk;
            if (g >= 0) {
                bf16x8 a3 = *(const bf16x8*)&h2w[(g >> 3) & 1][g & 7][n][aq * 8];
                bf16x8 wb = *(const bf16x8*)&W2f[(((long)g * 8 + wv) * 64 + lane) * 8];
                zacc = MFMA16(a3, wb, zacc);
            }
        }
        // acc2: h1 groups 8(w-1) .. 8w-1 (all < our groups, so apply to ALL own tiles)
        const int pH = (w - 1) & 1;
        const long g0 = 8 * (w - 1);
#pragma unroll
        for (int tt = 0; tt < 9; ++tt)
            if (tt < NT) w1A[tt] = *(const bf16x8*)&W1f[(((g0 + 0) * 64 + TLO + tt) * 64 + lane) * 8];
#pragma unroll 1
        for (int gk = 0; gk < 8; gk += 2) {
#pragma unroll
            for (int tt = 0; tt < 9; ++tt)
                if (tt < NT) w1B[tt] = *(const bf16x8*)&W1f[(((g0 + gk + 1) * 64 + TLO + tt) * 64 + lane) * 8];
            {
                bf16x8 af = *(const bf16x8*)&h1w[pH][gk][n][aq * 8];
#pragma unroll
                for (int tt = 0; tt < 9; ++tt)
                    if (tt < NT) acc2own[tt] = MFMA16(af, w1A[tt], acc2own[tt]);
            }
            if (gk + 2 < 8) {
#pragma unroll
                for (int tt = 0; tt < 9; ++tt)
                    if (tt < NT) w1A[tt] = *(const bf16x8*)&W1f[(((g0 + gk + 2) * 64 + TLO + tt) * 64 + lane) * 8];
            }
            {
                bf16x8 af = *(const bf16x8*)&h1w[pH][gk + 1][n][aq * 8];
#pragma unroll
                for (int tt = 0; tt < 9; ++tt)
                    if (tt < NT) acc2own[tt] = MFMA16(af, w1B[tt], acc2own[tt]);
            }
        }
    };

    // ---- one in-window step (k compile-time via full unroll) ----
    auto step = [&](int wq, int k, bf16x8 (&wApply)[9], bf16x8 (&wLoad)[9], bf16x8& w2S) {
        const int i = 8 * wq + k, g = i - 1;
        // apply h1[g] to own tiles >= tf0(g)  (k==0 is covered by catch-up)
        if (k > 0) {
            const int t0g = (off1(g) >> 4) - TLO;
            bf16x8 af = *(const bf16x8*)&h1w[(g >> 3) & 1][g & 7][n][aq * 8];
#pragma unroll
            for (int tt = 0; tt < 9; ++tt)
                if (tt < NT && tt >= t0g) acc2own[tt] = MFMA16(af, wApply[tt], acc2own[tt]);
        }
        // prefetch W1f group i (consumed next step's apply)
        if (k < 7) {
            const long gl = i;
#pragma unroll
            for (int tt = 0; tt < 9; ++tt)
                if (tt < NT) wLoad[tt] = *(const bf16x8*)&W1f[((gl * 64 + TLO + tt) * 64 + lane) * 8];
        }
        // finalize h2[g] from own accumulator (guarded static indexing, wave-uniform tf0)
        if (g >= 0) {
            const int og = off1(g), cg = cntg(g);
            const int tf0 = (og >> 4) - TLO, tfl = ((og + cg - 1) >> 4) - TLO;
            const int p2 = (g >> 3) & 1, s2 = g & 7;
            const int j0 = (tf0 + TLO) * 16 + n - og;
            const int j1 = (tfl + TLO) * 16 + n - og;
#pragma unroll
            for (int tt = 0; tt < 9; ++tt) {
                if (tt == tf0 && j0 >= 0 && j0 < cg) {
#pragma unroll
                    for (int r = 0; r < 4; ++r) {
                        float v = acc2own[tt][r];
                        h2w[p2][s2][aq * 4 + r][j0] = f2bf(v > 0.f ? v : 0.f);
                    }
                }
                if (tfl != tf0 && tt == tfl && j1 < cg) {
#pragma unroll
                    for (int r = 0; r < 4; ++r) {
                        float v = acc2own[tt][r];
                        h2w[p2][s2][aq * 4 + r][j1] = f2bf(v > 0.f ? v : 0.f);
                    }
                }
            }
            if (cg == 16 && n == 0) {   // keep col16 zero on 16-wide slot reuse
#pragma unroll
                for (int r = 0; r < 4; ++r) h2w[p2][s2][aq * 4 + r][16] = 0;
            }
        }
        // partial h1[i] MFMAs over xhist cols 0..i (col i+1 still zero here)
        f32x4 d0p = {0.f, 0.f, 0.f, 0.f}, d1p = {0.f, 0.f, 0.f, 0.f};
        const bool doH1 = (i < 63);
        if (doH1) {
            bf16x8 ax0 = *(const bf16x8*)&xhist[n][aq * 8];
            d0p = MFMA16(ax0, w0fa, d0p);
            if (i >= 32) {
                bf16x8 ax1 = *(const bf16x8*)&xhist[n][32 + aq * 8];
                d0p = MFMA16(ax1, w0fb, d0p);
            }
            if (i < 16) d1p = MFMA16(ax0, w0fc, d1p);
        }
        // zacc += h2[g] * W2 (same-wave LDS round trip)
        if (g >= 0) {
            bf16x8 af3 = *(const bf16x8*)&h2w[(g >> 3) & 1][g & 7][n][aq * 8];
            zacc = MFMA16(af3, w2S, zacc);
        }
        if (k < 7) {
            const long gp = (i + 1 < 63) ? i + 1 : 62;
            w2S = *(const bf16x8*)&W2f[((gp * 8 + wv) * 64 + lane) * 8];
        }
        // extract x_i (packed cols 2i = mu, 2i+1 = sigma live in lanes n0, n0+1)
        const int n0 = 2 * k;
        f32x4 sgv;
#pragma unroll
        for (int r = 0; r < 4; ++r) sgv[r] = __shfl_xor(zacc[r], 1);
        float xv[4];
        if (n == n0) {
#pragma unroll
            for (int r = 0; r < 4; ++r) {
                const float sg = sgv[r], mu = zacc[r];
                const float x = ureg[r] * __expf(sg) + mu;
                ldjacc[r] += sg;
                xv[r] = x;
                xLs[aq * 4 + r][i] = x;
                if (doH1) xhist[aq * 4 + r][i + 1] = f2bf(x);
            }
        }
        // rank-1 finish + publish h1[i]
        if (doH1) {
            const int pi = (i >> 3) & 1, si = i & 7;
#pragma unroll
            for (int r = 0; r < 4; ++r) {
                float xb = bfrnd(__shfl(xv[r], (lane & 48) | n0));
                float h = d0p[r] + xb * w0d[k];
                h1w[pi][si][aq * 4 + r][n] = f2bf(h > 0.f ? h : 0.f);
                if (n == 0) {
                    float h16 = (i < 16) ? (d1p[r] + xb * w0d16[k]) : 0.f;
                    h1w[pi][si][aq * 4 + r][16] = f2bf(h16 > 0.f ? h16 : 0.f);
                }
            }
            if (k < 7) {   // prefetch W0f frags for group i+1
                const long gb = i + 1;
                w0fa = *(const bf16x8*)&W0f[((gb * 4 + 0) * 64 + lane) * 8];
                w0fb = *(const bf16x8*)&W0f[((gb * 4 + 1) * 64 + lane) * 8];
                w0fc = *(const bf16x8*)&W0f[((gb * 4 + 2) * 64 + lane) * 8];
            }
        }
    };

    // ---- 8 windows, ONE barrier each ----
#pragma unroll 1
    for (int w = 0; w < 8; ++w) {
        if (wv == w) {
            __builtin_amdgcn_s_setprio(1);
            const long i0 = 8 * w;
            if (w > 0) w2E = *(const bf16x8*)&W2f[(((i0 - 1) * 8 + wv) * 64 + lane) * 8];
            w2O = *(const bf16x8*)&W2f[((i0 * 8 + wv) * 64 + lane) * 8];
            w0fa = *(const bf16x8*)&W0f[((i0 * 4 + 0) * 64 + lane) * 8];
            w0fb = *(const bf16x8*)&W0f[((i0 * 4 + 1) * 64 + lane) * 8];
            w0fc = *(const bf16x8*)&W0f[((i0 * 4 + 2) * 64 + lane) * 8];
#pragma unroll
            for (int k = 0; k < 8; ++k) {      // rank-1 coefficients for this window
                const int i = 8 * w + k;
                float v = 0.f, v16 = 0.f;
                if (i < 63) {
                    v = bfrnd(W0[unitOf(off1(i) + n) * 64 + i]);
                    if (i < 16) v16 = bfrnd(W0[unitOf(off1(i) + 16) * 64 + i]);
                }
                w0d[k] = v; w0d16[k] = v16;
            }
            if (w > 0) catchup(w);
#pragma unroll
            for (int k = 0; k < 8; k += 2) {
                step(w, k,     w1B, w1A, w2E);
                step(w, k + 1, w1A, w1B, w2O);
            }
#pragma unroll
            for (int r = 0; r < 4; ++r) {   // ldj partial for this wave's 8 steps
                float v = ldjacc[r];
                v += __shfl_xor(v, 2);
                v += __shfl_xor(v, 4);
                v += __shfl_xor(v, 8);
                if (n == 0) ldjpart[wv][aq * 4 + r] = v;
            }
            __builtin_amdgcn_s_setprio(0);
        } else if (w > 0 && wv > w) {
            catchup(w);
        }
        BAR();
    }

    if (t < 256) {
        int r = t >> 4, c = (t & 15) * 4;
        float4 v;
        v.x = xLs[r][c]; v.y = xLs[r][c + 1]; v.z = xLs[r][c + 2]; v.w = xLs[r][c + 3];
        *(float4*)&out[(long)(rowbase + r) * 64 + c] = v;
    }
    if (t < 16) {
        float s = 0.f;
#pragma unroll
        for (int w2 = 0; w2 < 8; ++w2) s += ldjpart[w2][t];
        out[(long)BATCH * 64 + rowbase + t] = s;
    }
}

extern "C" void kernel_launch(void* const* d_in, const int* in_sizes, int n_in,
                              void* d_out, int out_size, void* d_ws, size_t ws_size,
                              hipStream_t stream) {
    (void)in_sizes; (void)n_in; (void)out_size; (void)ws_size;
    const float* u  = (const float*)d_in[0];
    const float* W0 = (const float*)d_in[1];
    const float* b0 = (const float*)d_in[2];
    const float* W1 = (const float*)d_in[3];
    const float* b1 = (const float*)d_in[4];
    const float* W2 = (const float*)d_in[5];
    const float* b2 = (const float*)d_in[6];
    float* out = (float*)d_out;

    // d_ws layout (bytes): W1f 4,128,768 | W2f 516,096 | W0f 258,048 | b1p 4,096
    short* W1f = (short*)d_ws;
    short* W2f = (short*)((char*)d_ws + 4128768);
    short* W0f = (short*)((char*)d_ws + 4128768 + 516096);
    float* b1p = (float*)((char*)d_ws + 4128768 + 516096 + 258048);

    prep6<<<dim3(89), dim3(512), 0, stream>>>(W0, b0, W1, b1, W2, W1f, W2f, W0f, b1p);
    made7b<<<dim3(BATCH / 16), dim3(NTHR), 0, stream>>>(u, b2, W0, W1f, W2f, W0f, b1p, out);
}

// Round 3
// 412.664 us; speedup vs baseline: 1.0791x; 1.0791x over previous
//
#include <hip/hip_runtime.h>
#include <hip/hip_bf16.h>

#define BATCH 4096
#define NTHR 512

typedef __attribute__((ext_vector_type(8))) short bf16x8;
typedef __attribute__((ext_vector_type(4))) float f32x4;
typedef __attribute__((ext_vector_type(4))) short short4v;

// CK-style barrier: drain LDS only, leave global prefetches in flight
#define BAR() asm volatile("s_waitcnt lgkmcnt(0)\n\ts_barrier" ::: "memory")
#define MFMA16(a, b, c) __builtin_amdgcn_mfma_f32_16x16x32_bf16(a, b, c, 0, 0, 0)

// dh-sorted packing: group g (= degree) has cnt(g) units, prefix off1(g)
__host__ __device__ __forceinline__ int off1(int g) { return (g <= 16) ? 17 * g : 16 * g + 16; }
__host__ __device__ __forceinline__ int cntg(int g) { return (g < 16) ? 17 : 16; }
__host__ __device__ __forceinline__ int unitOf(int p) {
    int gp, jp;
    if (p < 272) { gp = p / 17; jp = p - gp * 17; }
    else         { gp = (p >> 4) - 1; jp = p & 15; }
    return gp + 63 * jp;
}
__device__ __forceinline__ short f2bf(float f) {
    __hip_bfloat16 h = __float2bfloat16(f);
    return *reinterpret_cast<short*>(&h);
}
__device__ __forceinline__ float bfrnd(float f) {
    __hip_bfloat16 h = __float2bfloat16(f);
    return __bfloat162float(h);
}

// ---------------- prep6: LDS-staged coalesced packing (512 thr) — unchanged ----------------
__global__ void prep6(const float* __restrict__ W0, const float* __restrict__ b0,
                      const float* __restrict__ W1, const float* __restrict__ b1,
                      const float* __restrict__ W2,
                      short* __restrict__ W1f, short* __restrict__ W2f,
                      short* __restrict__ W0f, float* __restrict__ b1p) {
    __shared__ short ws[16][1024];
    const int b = blockIdx.x, t = threadIdx.x;
    if (b < 72) {
        const bool isW1 = (b < 64);
        const int n = t >> 5;                 // staged slot 0..15
        int u;
        if (isW1) u = unitOf(b * 16 + n);
        else { const int c = b - 64; u = (n & 1) ? (64 + c * 8 + (n >> 1)) : (c * 8 + (n >> 1)); }
        const float* src = isW1 ? (W1 + (long)u * 1024) : (W2 + (long)u * 1024);
        const int c0 = (t & 31) * 4;
#pragma unroll
        for (int j = 0; j < 8; ++j) {
            int c = c0 + j * 128;
            float4 v = *(const float4*)&src[c];
            short4v sv;
            sv[0] = f2bf(v.x); sv[1] = f2bf(v.y); sv[2] = f2bf(v.z); sv[3] = f2bf(v.w);
            *(short4v*)&ws[n][c] = sv;
        }
        __syncthreads();
#pragma unroll 1
        for (int it = 0; it < 8; ++it) {
            int v = t + it * 512;
            if (v < 4032) {
                int g = v >> 6, lane2 = v & 63;
                int nn = lane2 & 15, aq2 = lane2 >> 4;
                bf16x8 pk;
#pragma unroll
                for (int e = 0; e < 8; ++e) {
                    int k = aq2 * 8 + e;
                    pk[e] = (k < cntg(g)) ? ws[nn][g + 63 * k] : (short)0;
                }
                if (isW1) *(bf16x8*)&W1f[(((long)g * 64 + b) * 64 + lane2) * 8] = pk;
                else      *(bf16x8*)&W2f[(((long)g * 8 + (b - 64)) * 64 + lane2) * 8] = pk;
            }
        }
    } else if (b < 88) {
        const int bb = b - 72;
#pragma unroll 1
        for (int j = 0; j < 16; ++j) {
            int q = t + j * 512;
            if (q < 8064) {
                int idx = bb * 8064 + q;
                int g = idx >> 11, rem = idx & 2047;
                int n2 = rem >> 10, kt = (rem >> 9) & 1, lane2 = (rem >> 3) & 63, e = rem & 7;
                int sl = n2 * 16 + (lane2 & 15);
                int kp = kt * 32 + ((lane2 >> 4) << 3) + e;
                float val = 0.f;
                if (sl < cntg(g)) {
                    int u = unitOf(off1(g) + sl);
                    if (kp == 0) val = b0[u];
                    else if (kp - 1 <= g) val = W0[u * 64 + kp - 1];
                }
                W0f[idx] = f2bf(val);
            }
        }
    } else {
        for (int p = t; p < 1024; p += 512) b1p[p] = b1[unitOf(p)];
    }
}

// ---------------- made7c: window scheme, spill-free ----------------
// Same algorithm as made7b (passing, absmax 0.015625). Changes are register-only:
// (a) amdgpu_waves_per_eu(2,2) pins allocator target at 2 waves/EU -> 256-VGPR budget
//     (8-wave block on 1 block/CU is exactly 2 waves/SIMD anyway; launch_bounds'
//     min-waves arg provably did NOT move the allocator off its 128-reg default).
// (b) in-window W1f/W2f prefetch single-buffered (load-to-use = 1 step ~600cy >> L2
//     ~200cy latency) and w0f/w0d/w2 prologue loads moved after catchup, cutting the
//     catchup-region register peak by ~70 regs as insurance.
__global__ __attribute__((amdgpu_flat_work_group_size(NTHR, NTHR)))
__attribute__((amdgpu_waves_per_eu(2, 2))) void made7c(
    const float* __restrict__ uin, const float* __restrict__ b2,
    const float* __restrict__ W0,
    const short* __restrict__ W1f, const short* __restrict__ W2f,
    const short* __restrict__ W0f, const float* __restrict__ b1p,
    float* __restrict__ out) {

    __shared__ __align__(16) short h1w[2][8][16][40];   // [par][slot][m][j], cols 17..31 stay 0
    __shared__ __align__(16) short h2w[2][8][16][40];
    __shared__ __align__(16) short xhist[16][80];       // [m][k']: k'=0 bias 1.0, k'=i+1 -> x_i
    __shared__ __align__(16) float uT[64][16];
    __shared__ __align__(16) float xLs[16][68];
    __shared__ float ldjpart[8][16];

    const int t = threadIdx.x, lane = t & 63, wv = t >> 6;
    const int n = lane & 15, aq = lane >> 4;
    const int rowbase = blockIdx.x * 16;

    {   // zero LDS (K pads must stay 0 forever)
        int* z1 = (int*)&h1w[0][0][0][0];
#pragma unroll 1
        for (int idx = t; idx < 5120; idx += NTHR) z1[idx] = 0;
        int* z2 = (int*)&h2w[0][0][0][0];
#pragma unroll 1
        for (int idx = t; idx < 5120; idx += NTHR) z2[idx] = 0;
        int* z3 = (int*)&xhist[0][0];
#pragma unroll 1
        for (int idx = t; idx < 640; idx += NTHR) z3[idx] = 0;
    }
    if (t < 256) {
        int r = t >> 4, c0 = (t & 15) * 4;
        float4 v = *(const float4*)&uin[(long)(rowbase + r) * 64 + c0];
        uT[c0 + 0][r] = v.x; uT[c0 + 1][r] = v.y; uT[c0 + 2][r] = v.z; uT[c0 + 3][r] = v.w;
    }

    // private tile range: tiles covering groups [gA, gB]
    const int gA = (wv == 0) ? 0 : 8 * wv - 1;
    const int gB = (8 * wv + 6 > 62) ? 62 : 8 * wv + 6;
    const int TLO = off1(gA) >> 4;
    const int NT = ((off1(gB) + cntg(gB) - 1) >> 4) - TLO + 1;   // 8 or 9

    f32x4 acc2own[9];
#pragma unroll
    for (int tt = 0; tt < 9; ++tt) {
        float bb = (tt < NT) ? b1p[(TLO + tt) * 16 + n] : 0.f;
        acc2own[tt] = (f32x4){bb, bb, bb, bb};
    }
    f32x4 zacc;
    {
        int pc = wv * 16 + n;               // packed z col; orig r = (pc>>1)+64*(pc&1)
        float bz = b2[(pc >> 1) + 64 * (pc & 1)];
        zacc = (f32x4){bz, bz, bz, bz};
    }

    // rank-1 coefficients: filled in publisher prologue (only active wave loads them)
    float w0d[8], w0d16[8];

    f32x4 ldjacc = {0.f, 0.f, 0.f, 0.f};
    bf16x8 w1A[9], w1B[9], w2S, w0fa, w0fb, w0fc;

    BAR();
    if (t < 16) xhist[t][0] = (short)0x3F80;   // bias col = 1.0 (wave 0, same-wave first use)
    float ureg[4];
#pragma unroll
    for (int r = 0; r < 4; ++r) ureg[r] = uT[8 * wv + (n >> 1)][aq * 4 + r];

    // ---- window-boundary catch-up: batch-apply previous window's groups ----
    auto catchup = [&](int w) {
        // zacc: groups 8w-9 .. 8w-2
#pragma unroll
        for (int gk = 0; gk < 8; ++gk) {
            const int g = 8 * w - 9 + gk;
            if (g >= 0) {
                bf16x8 a3 = *(const bf16x8*)&h2w[(g >> 3) & 1][g & 7][n][aq * 8];
                bf16x8 wb = *(const bf16x8*)&W2f[(((long)g * 8 + wv) * 64 + lane) * 8];
                zacc = MFMA16(a3, wb, zacc);
            }
        }
        // acc2: h1 groups 8(w-1) .. 8w-1 (all < our groups, so apply to ALL own tiles)
        const int pH = (w - 1) & 1;
        const long g0 = 8 * (w - 1);
#pragma unroll
        for (int tt = 0; tt < 9; ++tt)
            if (tt < NT) w1A[tt] = *(const bf16x8*)&W1f[(((g0 + 0) * 64 + TLO + tt) * 64 + lane) * 8];
#pragma unroll 1
        for (int gk = 0; gk < 8; gk += 2) {
#pragma unroll
            for (int tt = 0; tt < 9; ++tt)
                if (tt < NT) w1B[tt] = *(const bf16x8*)&W1f[(((g0 + gk + 1) * 64 + TLO + tt) * 64 + lane) * 8];
            {
                bf16x8 af = *(const bf16x8*)&h1w[pH][gk][n][aq * 8];
#pragma unroll
                for (int tt = 0; tt < 9; ++tt)
                    if (tt < NT) acc2own[tt] = MFMA16(af, w1A[tt], acc2own[tt]);
            }
            if (gk + 2 < 8) {
#pragma unroll
                for (int tt = 0; tt < 9; ++tt)
                    if (tt < NT) w1A[tt] = *(const bf16x8*)&W1f[(((g0 + gk + 2) * 64 + TLO + tt) * 64 + lane) * 8];
            }
            {
                bf16x8 af = *(const bf16x8*)&h1w[pH][gk + 1][n][aq * 8];
#pragma unroll
                for (int tt = 0; tt < 9; ++tt)
                    if (tt < NT) acc2own[tt] = MFMA16(af, w1B[tt], acc2own[tt]);
            }
        }
    };

    // ---- one in-window step (k compile-time via full unroll) ----
    // w1P: single-buffered W1f frags. At step k it holds group i-1 (loaded step k-1);
    // after the apply it is reloaded with group i. w2S likewise holds group i-1 on entry.
    auto step = [&](int wq, int k, bf16x8 (&w1P)[9], bf16x8& w2S_) {
        const int i = 8 * wq + k, g = i - 1;
        // apply h1[g] to own tiles >= tf0(g)  (k==0 is covered by catch-up)
        if (k > 0) {
            const int t0g = (off1(g) >> 4) - TLO;
            bf16x8 af = *(const bf16x8*)&h1w[(g >> 3) & 1][g & 7][n][aq * 8];
#pragma unroll
            for (int tt = 0; tt < 9; ++tt)
                if (tt < NT && tt >= t0g) acc2own[tt] = MFMA16(af, w1P[tt], acc2own[tt]);
        }
        // reload w1P with group i (consumed by next step's apply)
        if (k < 7) {
            const long gl = i;
#pragma unroll
            for (int tt = 0; tt < 9; ++tt)
                if (tt < NT) w1P[tt] = *(const bf16x8*)&W1f[((gl * 64 + TLO + tt) * 64 + lane) * 8];
        }
        // finalize h2[g] from own accumulator (guarded static indexing, wave-uniform tf0)
        if (g >= 0) {
            const int og = off1(g), cg = cntg(g);
            const int tf0 = (og >> 4) - TLO, tfl = ((og + cg - 1) >> 4) - TLO;
            const int p2 = (g >> 3) & 1, s2 = g & 7;
            const int j0 = (tf0 + TLO) * 16 + n - og;
            const int j1 = (tfl + TLO) * 16 + n - og;
#pragma unroll
            for (int tt = 0; tt < 9; ++tt) {
                if (tt == tf0 && j0 >= 0 && j0 < cg) {
#pragma unroll
                    for (int r = 0; r < 4; ++r) {
                        float v = acc2own[tt][r];
                        h2w[p2][s2][aq * 4 + r][j0] = f2bf(v > 0.f ? v : 0.f);
                    }
                }
                if (tfl != tf0 && tt == tfl && j1 < cg) {
#pragma unroll
                    for (int r = 0; r < 4; ++r) {
                        float v = acc2own[tt][r];
                        h2w[p2][s2][aq * 4 + r][j1] = f2bf(v > 0.f ? v : 0.f);
                    }
                }
            }
            if (cg == 16 && n == 0) {   // keep col16 zero on 16-wide slot reuse
#pragma unroll
                for (int r = 0; r < 4; ++r) h2w[p2][s2][aq * 4 + r][16] = 0;
            }
        }
        // partial h1[i] MFMAs over xhist cols 0..i (col i+1 still zero here)
        f32x4 d0p = {0.f, 0.f, 0.f, 0.f}, d1p = {0.f, 0.f, 0.f, 0.f};
        const bool doH1 = (i < 63);
        if (doH1) {
            bf16x8 ax0 = *(const bf16x8*)&xhist[n][aq * 8];
            d0p = MFMA16(ax0, w0fa, d0p);
            if (i >= 32) {
                bf16x8 ax1 = *(const bf16x8*)&xhist[n][32 + aq * 8];
                d0p = MFMA16(ax1, w0fb, d0p);
            }
            if (i < 16) d1p = MFMA16(ax0, w0fc, d1p);
        }
        // zacc += h2[g] * W2 (same-wave LDS round trip)
        if (g >= 0) {
            bf16x8 af3 = *(const bf16x8*)&h2w[(g >> 3) & 1][g & 7][n][aq * 8];
            zacc = MFMA16(af3, w2S_, zacc);
        }
        if (k < 7) {   // reload w2S with group i (consumed next step)
            const long gp = (i < 63) ? i : 62;
            w2S_ = *(const bf16x8*)&W2f[((gp * 8 + wv) * 64 + lane) * 8];
        }
        // extract x_i (packed cols 2i = mu, 2i+1 = sigma live in lanes n0, n0+1)
        const int n0 = 2 * k;
        f32x4 sgv;
#pragma unroll
        for (int r = 0; r < 4; ++r) sgv[r] = __shfl_xor(zacc[r], 1);
        float xv[4];
        if (n == n0) {
#pragma unroll
            for (int r = 0; r < 4; ++r) {
                const float sg = sgv[r], mu = zacc[r];
                const float x = ureg[r] * __expf(sg) + mu;
                ldjacc[r] += sg;
                xv[r] = x;
                xLs[aq * 4 + r][i] = x;
                if (doH1) xhist[aq * 4 + r][i + 1] = f2bf(x);
            }
        }
        // rank-1 finish + publish h1[i]
        if (doH1) {
            const int pi = (i >> 3) & 1, si = i & 7;
#pragma unroll
            for (int r = 0; r < 4; ++r) {
                float xb = bfrnd(__shfl(xv[r], (lane & 48) | n0));
                float h = d0p[r] + xb * w0d[k];
                h1w[pi][si][aq * 4 + r][n] = f2bf(h > 0.f ? h : 0.f);
                if (n == 0) {
                    float h16 = (i < 16) ? (d1p[r] + xb * w0d16[k]) : 0.f;
                    h1w[pi][si][aq * 4 + r][16] = f2bf(h16 > 0.f ? h16 : 0.f);
                }
            }
            if (k < 7) {   // prefetch W0f frags for group i+1
                const long gb = i + 1;
                w0fa = *(const bf16x8*)&W0f[((gb * 4 + 0) * 64 + lane) * 8];
                w0fb = *(const bf16x8*)&W0f[((gb * 4 + 1) * 64 + lane) * 8];
                w0fc = *(const bf16x8*)&W0f[((gb * 4 + 2) * 64 + lane) * 8];
            }
        }
    };

    // ---- 8 windows, ONE barrier each ----
#pragma unroll 1
    for (int w = 0; w < 8; ++w) {
        if (wv == w) {
            __builtin_amdgcn_s_setprio(1);
            if (w > 0) catchup(w);
            // publisher prologue AFTER catchup: keeps these out of the catchup
            // register-pressure peak. L2-hot loads, ~200cy, covered by step-0 slack.
            const long i0 = 8 * w;
            {
                const long gz = (w > 0) ? (i0 - 1) : 0;
                w2S = *(const bf16x8*)&W2f[((gz * 8 + wv) * 64 + lane) * 8];
            }
            w0fa = *(const bf16x8*)&W0f[((i0 * 4 + 0) * 64 + lane) * 8];
            w0fb = *(const bf16x8*)&W0f[((i0 * 4 + 1) * 64 + lane) * 8];
            w0fc = *(const bf16x8*)&W0f[((i0 * 4 + 2) * 64 + lane) * 8];
#pragma unroll
            for (int k = 0; k < 8; ++k) {      // rank-1 coefficients for this window
                const int i = 8 * w + k;
                float v = 0.f, v16 = 0.f;
                if (i < 63) {
                    v = bfrnd(W0[unitOf(off1(i) + n) * 64 + i]);
                    if (i < 16) v16 = bfrnd(W0[unitOf(off1(i) + 16) * 64 + i]);
                }
                w0d[k] = v; w0d16[k] = v16;
            }
#pragma unroll
            for (int k = 0; k < 8; k += 2) {
                step(w, k,     w1A, w2S);
                step(w, k + 1, w1A, w2S);
            }
#pragma unroll
            for (int r = 0; r < 4; ++r) {   // ldj partial for this wave's 8 steps
                float v = ldjacc[r];
                v += __shfl_xor(v, 2);
                v += __shfl_xor(v, 4);
                v += __shfl_xor(v, 8);
                if (n == 0) ldjpart[wv][aq * 4 + r] = v;
            }
            __builtin_amdgcn_s_setprio(0);
        } else if (w > 0 && wv > w) {
            catchup(w);
        }
        BAR();
    }

    if (t < 256) {
        int r = t >> 4, c = (t & 15) * 4;
        float4 v;
        v.x = xLs[r][c]; v.y = xLs[r][c + 1]; v.z = xLs[r][c + 2]; v.w = xLs[r][c + 3];
        *(float4*)&out[(long)(rowbase + r) * 64 + c] = v;
    }
    if (t < 16) {
        float s = 0.f;
#pragma unroll
        for (int w2 = 0; w2 < 8; ++w2) s += ldjpart[w2][t];
        out[(long)BATCH * 64 + rowbase + t] = s;
    }
}

extern "C" void kernel_launch(void* const* d_in, const int* in_sizes, int n_in,
                              void* d_out, int out_size, void* d_ws, size_t ws_size,
                              hipStream_t stream) {
    (void)in_sizes; (void)n_in; (void)out_size; (void)ws_size;
    const float* u  = (const float*)d_in[0];
    const float* W0 = (const float*)d_in[1];
    const float* b0 = (const float*)d_in[2];
    const float* W1 = (const float*)d_in[3];
    const float* b1 = (const float*)d_in[4];
    const float* W2 = (const float*)d_in[5];
    const float* b2 = (const float*)d_in[6];
    float* out = (float*)d_out;

    // d_ws layout (bytes): W1f 4,128,768 | W2f 516,096 | W0f 258,048 | b1p 4,096
    short* W1f = (short*)d_ws;
    short* W2f = (short*)((char*)d_ws + 4128768);
    short* W0f = (short*)((char*)d_ws + 4128768 + 516096);
    float* b1p = (float*)((char*)d_ws + 4128768 + 516096 + 258048);

    prep6<<<dim3(89), dim3(512), 0, stream>>>(W0, b0, W1, b1, W2, W1f, W2f, W0f, b1p);
    made7c<<<dim3(BATCH / 16), dim3(NTHR), 0, stream>>>(u, b2, W0, W1f, W2f, W0f, b1p, out);
}

// Round 4
// 372.956 us; speedup vs baseline: 1.1939x; 1.1065x over previous
//
#include <hip/hip_runtime.h>
#include <hip/hip_bf16.h>

#define BATCH 4096
#define NTHR 512

typedef __attribute__((ext_vector_type(8))) short bf16x8;
typedef __attribute__((ext_vector_type(4))) float f32x4;
typedef __attribute__((ext_vector_type(4))) short short4v;

// CK-style barrier: drain LDS only, leave global prefetches in flight
#define BAR() asm volatile("s_waitcnt lgkmcnt(0)\n\ts_barrier" ::: "memory")
#define MFMA16(a, b, c) __builtin_amdgcn_mfma_f32_16x16x32_bf16(a, b, c, 0, 0, 0)

// expand OP over the 9 owned tiles (named registers, never an array)
#define TT_EACH(OP) OP(0) OP(1) OP(2) OP(3) OP(4) OP(5) OP(6) OP(7) OP(8)

// dh-sorted packing: group g (= degree) has cnt(g) units, prefix off1(g)
__host__ __device__ __forceinline__ int off1(int g) { return (g <= 16) ? 17 * g : 16 * g + 16; }
__host__ __device__ __forceinline__ int cntg(int g) { return (g < 16) ? 17 : 16; }
__host__ __device__ __forceinline__ int unitOf(int p) {
    int gp, jp;
    if (p < 272) { gp = p / 17; jp = p - gp * 17; }
    else         { gp = (p >> 4) - 1; jp = p & 15; }
    return gp + 63 * jp;
}
__device__ __forceinline__ short f2bf(float f) {
    __hip_bfloat16 h = __float2bfloat16(f);
    return *reinterpret_cast<short*>(&h);
}
__device__ __forceinline__ float bfrnd(float f) {
    __hip_bfloat16 h = __float2bfloat16(f);
    return __bfloat162float(h);
}

// ---------------- prep6: LDS-staged coalesced packing (512 thr) — unchanged ----------------
__global__ void prep6(const float* __restrict__ W0, const float* __restrict__ b0,
                      const float* __restrict__ W1, const float* __restrict__ b1,
                      const float* __restrict__ W2,
                      short* __restrict__ W1f, short* __restrict__ W2f,
                      short* __restrict__ W0f, float* __restrict__ b1p) {
    __shared__ short ws[16][1024];
    const int b = blockIdx.x, t = threadIdx.x;
    if (b < 72) {
        const bool isW1 = (b < 64);
        const int n = t >> 5;                 // staged slot 0..15
        int u;
        if (isW1) u = unitOf(b * 16 + n);
        else { const int c = b - 64; u = (n & 1) ? (64 + c * 8 + (n >> 1)) : (c * 8 + (n >> 1)); }
        const float* src = isW1 ? (W1 + (long)u * 1024) : (W2 + (long)u * 1024);
        const int c0 = (t & 31) * 4;
#pragma unroll
        for (int j = 0; j < 8; ++j) {
            int c = c0 + j * 128;
            float4 v = *(const float4*)&src[c];
            short4v sv;
            sv[0] = f2bf(v.x); sv[1] = f2bf(v.y); sv[2] = f2bf(v.z); sv[3] = f2bf(v.w);
            *(short4v*)&ws[n][c] = sv;
        }
        __syncthreads();
#pragma unroll 1
        for (int it = 0; it < 8; ++it) {
            int v = t + it * 512;
            if (v < 4032) {
                int g = v >> 6, lane2 = v & 63;
                int nn = lane2 & 15, aq2 = lane2 >> 4;
                bf16x8 pk;
#pragma unroll
                for (int e = 0; e < 8; ++e) {
                    int k = aq2 * 8 + e;
                    pk[e] = (k < cntg(g)) ? ws[nn][g + 63 * k] : (short)0;
                }
                if (isW1) *(bf16x8*)&W1f[(((long)g * 64 + b) * 64 + lane2) * 8] = pk;
                else      *(bf16x8*)&W2f[(((long)g * 8 + (b - 64)) * 64 + lane2) * 8] = pk;
            }
        }
    } else if (b < 88) {
        const int bb = b - 72;
#pragma unroll 1
        for (int j = 0; j < 16; ++j) {
            int q = t + j * 512;
            if (q < 8064) {
                int idx = bb * 8064 + q;
                int g = idx >> 11, rem = idx & 2047;
                int n2 = rem >> 10, kt = (rem >> 9) & 1, lane2 = (rem >> 3) & 63, e = rem & 7;
                int sl = n2 * 16 + (lane2 & 15);
                int kp = kt * 32 + ((lane2 >> 4) << 3) + e;
                float val = 0.f;
                if (sl < cntg(g)) {
                    int u = unitOf(off1(g) + sl);
                    if (kp == 0) val = b0[u];
                    else if (kp - 1 <= g) val = W0[u * 64 + kp - 1];
                }
                W0f[idx] = f2bf(val);
            }
        }
    } else {
        for (int p = t; p < 1024; p += 512) b1p[p] = b1[unitOf(p)];
    }
}

// ---------------- made7d: window scheme, fully scalarized (no demotable aggregates) ----------------
// Algorithm identical to made7c (passed 3x, absmax 0.015625 == made6). Mechanical change:
// every C array that SROA could demote to scratch is gone —
//   acc2own[9] -> a0..a8, W1-prefetch -> q0..q8 (single-buffered),
//   w0d[8]/w0d16[8] -> two rotating scalars gathered 1 step ahead,
//   ureg/xv/sgv -> f32x4 (first-class vector regs, static subscripts only).
// Round 1-3 evidence: 150+ MB scratch traffic at VGPR_Count==128 under THREE different
// budget knobs => frontend alloca demotion, not regalloc pressure.
__global__ __attribute__((amdgpu_flat_work_group_size(NTHR, NTHR)))
__attribute__((amdgpu_waves_per_eu(2, 2))) void made7d(
    const float* __restrict__ uin, const float* __restrict__ b2,
    const float* __restrict__ W0,
    const short* __restrict__ W1f, const short* __restrict__ W2f,
    const short* __restrict__ W0f, const float* __restrict__ b1p,
    float* __restrict__ out) {

    __shared__ __align__(16) short h1w[2][8][16][40];   // [par][slot][m][j], cols 17..31 stay 0
    __shared__ __align__(16) short h2w[2][8][16][40];
    __shared__ __align__(16) short xhist[16][80];       // [m][k']: k'=0 bias 1.0, k'=i+1 -> x_i
    __shared__ __align__(16) float uT[64][16];
    __shared__ __align__(16) float xLs[16][68];
    __shared__ float ldjpart[8][16];

    const int t = threadIdx.x, lane = t & 63, wv = t >> 6;
    const int n = lane & 15, aq = lane >> 4;
    const int rowbase = blockIdx.x * 16;

    {   // zero LDS (K pads must stay 0 forever)
        int* z1 = (int*)&h1w[0][0][0][0];
#pragma unroll 1
        for (int idx = t; idx < 5120; idx += NTHR) z1[idx] = 0;
        int* z2 = (int*)&h2w[0][0][0][0];
#pragma unroll 1
        for (int idx = t; idx < 5120; idx += NTHR) z2[idx] = 0;
        int* z3 = (int*)&xhist[0][0];
#pragma unroll 1
        for (int idx = t; idx < 640; idx += NTHR) z3[idx] = 0;
    }
    if (t < 256) {
        int r = t >> 4, c0 = (t & 15) * 4;
        float4 v = *(const float4*)&uin[(long)(rowbase + r) * 64 + c0];
        uT[c0 + 0][r] = v.x; uT[c0 + 1][r] = v.y; uT[c0 + 2][r] = v.z; uT[c0 + 3][r] = v.w;
    }

    // private tile range: tiles covering groups [gA, gB]
    const int gA = (wv == 0) ? 0 : 8 * wv - 1;
    const int gB = (8 * wv + 6 > 62) ? 62 : 8 * wv + 6;
    const int TLO = off1(gA) >> 4;
    const int NT = ((off1(gB) + cntg(gB) - 1) >> 4) - TLO + 1;   // 8 or 9

    // named accumulator tiles (never an array)
#define DECL_A(tt) f32x4 a##tt;
    TT_EACH(DECL_A)
#undef DECL_A
#define INIT_A(tt) { float bb_ = (tt < NT) ? b1p[(TLO + tt) * 16 + n] : 0.f; a##tt = (f32x4){bb_, bb_, bb_, bb_}; }
    TT_EACH(INIT_A)
#undef INIT_A

    // named W1 fragment registers (single-buffered prefetch)
#define DECL_Q(tt) bf16x8 q##tt;
    TT_EACH(DECL_Q)
#undef DECL_Q

    f32x4 zacc;
    {
        int pc = wv * 16 + n;               // packed z col; orig r = (pc>>1)+64*(pc&1)
        float bz = b2[(pc >> 1) + 64 * (pc & 1)];
        zacc = (f32x4){bz, bz, bz, bz};
    }

    f32x4 ldjacc = {0.f, 0.f, 0.f, 0.f};
    bf16x8 w2S, w0fa, w0fb, w0fc;
    float w0dA = 0.f, w0d16A = 0.f, w0dB = 0.f, w0d16B = 0.f;   // rotating rank-1 coeffs

    BAR();
    if (t < 16) xhist[t][0] = (short)0x3F80;   // bias col = 1.0 (wave 0, same-wave first use)
    f32x4 ureg;
#pragma unroll
    for (int r = 0; r < 4; ++r) ureg[r] = uT[8 * wv + (n >> 1)][aq * 4 + r];

    // ---- window-boundary catch-up: batch-apply previous window's groups ----
    auto catchup = [&](int w) {
        // zacc: groups 8w-9 .. 8w-2
#pragma unroll
        for (int gk = 0; gk < 8; ++gk) {
            const int g = 8 * w - 9 + gk;
            if (g >= 0) {
                bf16x8 a3 = *(const bf16x8*)&h2w[(g >> 3) & 1][g & 7][n][aq * 8];
                bf16x8 wb = *(const bf16x8*)&W2f[(((long)g * 8 + wv) * 64 + lane) * 8];
                zacc = MFMA16(a3, wb, zacc);
            }
        }
        // acc2: h1 groups 8(w-1) .. 8w-1 (all < our groups, so apply to ALL own tiles)
        const int pH = (w - 1) & 1;
        const long g0 = 8 * (w - 1);
#pragma unroll 1
        for (int gk = 0; gk < 8; ++gk) {
            bf16x8 af = *(const bf16x8*)&h1w[pH][gk][n][aq * 8];   // LDS read early, overlaps L2
            const long gg = g0 + gk;
#define LQ(tt) if (tt < NT) q##tt = *(const bf16x8*)&W1f[((gg * 64 + TLO + tt) * 64 + lane) * 8];
            TT_EACH(LQ)
#undef LQ
#define AQ(tt) if (tt < NT) a##tt = MFMA16(af, q##tt, a##tt);
            TT_EACH(AQ)
#undef AQ
        }
    };

    // ---- one in-window step (k compile-time at every call site) ----
    // q0..q8 hold W1f group i-1 on entry (loaded previous step / covered by catchup at k==0).
    auto step = [&](int wq, int k, float& w0dU, float& w0d16U, float& w0dP, float& w0d16P) {
        const int i = 8 * wq + k, g = i - 1;
        // apply h1[g] to own tiles >= tf0(g)  (k==0 is covered by catch-up)
        if (k > 0) {
            const int t0g = (off1(g) >> 4) - TLO;
            bf16x8 af = *(const bf16x8*)&h1w[(g >> 3) & 1][g & 7][n][aq * 8];
#define AP(tt) if (tt < NT && tt >= t0g) a##tt = MFMA16(af, q##tt, a##tt);
            TT_EACH(AP)
#undef AP
        }
        // reload q with group i (consumed by next step's apply); prefetch next coeffs
        if (k < 7) {
            const long gl = i;
#define LQ(tt) if (tt < NT) q##tt = *(const bf16x8*)&W1f[((gl * 64 + TLO + tt) * 64 + lane) * 8];
            TT_EACH(LQ)
#undef LQ
            const int i2 = i + 1;
            w0dP = (i2 < 63) ? bfrnd(W0[unitOf(off1(i2) + n) * 64 + i2]) : 0.f;
            w0d16P = (i2 < 16) ? bfrnd(W0[unitOf(off1(i2) + 16) * 64 + i2]) : 0.f;
        }
        // finalize h2[g] from own accumulator (scalar-guarded named tiles)
        if (g >= 0) {
            const int og = off1(g), cg = cntg(g);
            const int tf0 = (og >> 4) - TLO, tfl = ((og + cg - 1) >> 4) - TLO;
            const int p2 = (g >> 3) & 1, s2 = g & 7;
            const int j0 = (tf0 + TLO) * 16 + n - og;
            const int j1 = (tfl + TLO) * 16 + n - og;
#define F0(tt) if (tt == tf0 && j0 >= 0 && j0 < cg) { \
                h2w[p2][s2][aq * 4 + 0][j0] = f2bf(a##tt[0] > 0.f ? a##tt[0] : 0.f); \
                h2w[p2][s2][aq * 4 + 1][j0] = f2bf(a##tt[1] > 0.f ? a##tt[1] : 0.f); \
                h2w[p2][s2][aq * 4 + 2][j0] = f2bf(a##tt[2] > 0.f ? a##tt[2] : 0.f); \
                h2w[p2][s2][aq * 4 + 3][j0] = f2bf(a##tt[3] > 0.f ? a##tt[3] : 0.f); }
            TT_EACH(F0)
#undef F0
#define F1(tt) if (tfl != tf0 && tt == tfl && j1 < cg) { \
                h2w[p2][s2][aq * 4 + 0][j1] = f2bf(a##tt[0] > 0.f ? a##tt[0] : 0.f); \
                h2w[p2][s2][aq * 4 + 1][j1] = f2bf(a##tt[1] > 0.f ? a##tt[1] : 0.f); \
                h2w[p2][s2][aq * 4 + 2][j1] = f2bf(a##tt[2] > 0.f ? a##tt[2] : 0.f); \
                h2w[p2][s2][aq * 4 + 3][j1] = f2bf(a##tt[3] > 0.f ? a##tt[3] : 0.f); }
            TT_EACH(F1)
#undef F1
            if (cg == 16 && n == 0) {   // keep col16 zero on 16-wide slot reuse
#pragma unroll
                for (int r = 0; r < 4; ++r) h2w[p2][s2][aq * 4 + r][16] = 0;
            }
        }
        // partial h1[i] MFMAs over xhist cols 0..i (col i+1 still zero here)
        f32x4 d0p = {0.f, 0.f, 0.f, 0.f}, d1p = {0.f, 0.f, 0.f, 0.f};
        const bool doH1 = (i < 63);
        if (doH1) {
            bf16x8 ax0 = *(const bf16x8*)&xhist[n][aq * 8];
            d0p = MFMA16(ax0, w0fa, d0p);
            if (i >= 32) {
                bf16x8 ax1 = *(const bf16x8*)&xhist[n][32 + aq * 8];
                d0p = MFMA16(ax1, w0fb, d0p);
            }
            if (i < 16) d1p = MFMA16(ax0, w0fc, d1p);
        }
        // zacc += h2[g] * W2 (same-wave LDS round trip)
        if (g >= 0) {
            bf16x8 af3 = *(const bf16x8*)&h2w[(g >> 3) & 1][g & 7][n][aq * 8];
            zacc = MFMA16(af3, w2S, zacc);
        }
        if (k < 7) {   // reload w2S with group i (consumed next step)
            const long gp = (i < 63) ? i : 62;
            w2S = *(const bf16x8*)&W2f[((gp * 8 + wv) * 64 + lane) * 8];
        }
        // extract x_i (packed cols 2i = mu, 2i+1 = sigma live in lanes n0, n0+1)
        const int n0 = 2 * k;
        f32x4 sgv;
#pragma unroll
        for (int r = 0; r < 4; ++r) sgv[r] = __shfl_xor(zacc[r], 1);
        f32x4 xv;
        if (n == n0) {
#pragma unroll
            for (int r = 0; r < 4; ++r) {
                const float sg = sgv[r], mu = zacc[r];
                const float x = ureg[r] * __expf(sg) + mu;
                ldjacc[r] += sg;
                xv[r] = x;
                xLs[aq * 4 + r][i] = x;
                if (doH1) xhist[aq * 4 + r][i + 1] = f2bf(x);
            }
        }
        // rank-1 finish + publish h1[i]
        if (doH1) {
            const int pi = (i >> 3) & 1, si = i & 7;
#pragma unroll
            for (int r = 0; r < 4; ++r) {
                float xb = bfrnd(__shfl(xv[r], (lane & 48) | n0));
                float h = d0p[r] + xb * w0dU;
                h1w[pi][si][aq * 4 + r][n] = f2bf(h > 0.f ? h : 0.f);
                if (n == 0) {
                    float h16 = (i < 16) ? (d1p[r] + xb * w0d16U) : 0.f;
                    h1w[pi][si][aq * 4 + r][16] = f2bf(h16 > 0.f ? h16 : 0.f);
                }
            }
            if (k < 7) {   // prefetch W0f frags for group i+1
                const long gb = (i + 1 < 63) ? i + 1 : 62;
                w0fa = *(const bf16x8*)&W0f[((gb * 4 + 0) * 64 + lane) * 8];
                w0fb = *(const bf16x8*)&W0f[((gb * 4 + 1) * 64 + lane) * 8];
                w0fc = *(const bf16x8*)&W0f[((gb * 4 + 2) * 64 + lane) * 8];
            }
        }
    };

    // ---- 8 windows, ONE barrier each ----
#pragma unroll 1
    for (int w = 0; w < 8; ++w) {
        if (wv == w) {
            __builtin_amdgcn_s_setprio(1);
            if (w > 0) catchup(w);
            // publisher prologue AFTER catchup (keeps it out of the catchup pressure peak)
            const int i0 = 8 * w;
            {
                const long gz = (w > 0) ? (i0 - 1) : 0;
                w2S = *(const bf16x8*)&W2f[((gz * 8 + wv) * 64 + lane) * 8];
            }
            w0fa = *(const bf16x8*)&W0f[(((long)i0 * 4 + 0) * 64 + lane) * 8];
            w0fb = *(const bf16x8*)&W0f[(((long)i0 * 4 + 1) * 64 + lane) * 8];
            w0fc = *(const bf16x8*)&W0f[(((long)i0 * 4 + 2) * 64 + lane) * 8];
            w0dA = bfrnd(W0[unitOf(off1(i0) + n) * 64 + i0]);                        // i0<=56<63
            w0d16A = (i0 < 16) ? bfrnd(W0[unitOf(off1(i0) + 16) * 64 + i0]) : 0.f;
            step(w, 0, w0dA, w0d16A, w0dB, w0d16B);
            step(w, 1, w0dB, w0d16B, w0dA, w0d16A);
            step(w, 2, w0dA, w0d16A, w0dB, w0d16B);
            step(w, 3, w0dB, w0d16B, w0dA, w0d16A);
            step(w, 4, w0dA, w0d16A, w0dB, w0d16B);
            step(w, 5, w0dB, w0d16B, w0dA, w0d16A);
            step(w, 6, w0dA, w0d16A, w0dB, w0d16B);
            step(w, 7, w0dB, w0d16B, w0dA, w0d16A);
#pragma unroll
            for (int r = 0; r < 4; ++r) {   // ldj partial for this wave's 8 steps
                float v = ldjacc[r];
                v += __shfl_xor(v, 2);
                v += __shfl_xor(v, 4);
                v += __shfl_xor(v, 8);
                if (n == 0) ldjpart[wv][aq * 4 + r] = v;
            }
            __builtin_amdgcn_s_setprio(0);
        } else if (w > 0 && wv > w) {
            catchup(w);
        }
        BAR();
    }

    if (t < 256) {
        int r = t >> 4, c = (t & 15) * 4;
        float4 v;
        v.x = xLs[r][c]; v.y = xLs[r][c + 1]; v.z = xLs[r][c + 2]; v.w = xLs[r][c + 3];
        *(float4*)&out[(long)(rowbase + r) * 64 + c] = v;
    }
    if (t < 16) {
        float s = 0.f;
#pragma unroll
        for (int w2 = 0; w2 < 8; ++w2) s += ldjpart[w2][t];
        out[(long)BATCH * 64 + rowbase + t] = s;
    }
}

extern "C" void kernel_launch(void* const* d_in, const int* in_sizes, int n_in,
                              void* d_out, int out_size, void* d_ws, size_t ws_size,
                              hipStream_t stream) {
    (void)in_sizes; (void)n_in; (void)out_size; (void)ws_size;
    const float* u  = (const float*)d_in[0];
    const float* W0 = (const float*)d_in[1];
    const float* b0 = (const float*)d_in[2];
    const float* W1 = (const float*)d_in[3];
    const float* b1 = (const float*)d_in[4];
    const float* W2 = (const float*)d_in[5];
    const float* b2 = (const float*)d_in[6];
    float* out = (float*)d_out;

    // d_ws layout (bytes): W1f 4,128,768 | W2f 516,096 | W0f 258,048 | b1p 4,096
    short* W1f = (short*)d_ws;
    short* W2f = (short*)((char*)d_ws + 4128768);
    short* W0f = (short*)((char*)d_ws + 4128768 + 516096);
    float* b1p = (float*)((char*)d_ws + 4128768 + 516096 + 258048);

    prep6<<<dim3(89), dim3(512), 0, stream>>>(W0, b0, W1, b1, W2, W1f, W2f, W0f, b1p);
    made7d<<<dim3(BATCH / 16), dim3(NTHR), 0, stream>>>(u, b2, W0, W1f, W2f, W0f, b1p, out);
}

// Round 5
// 264.852 us; speedup vs baseline: 1.6813x; 1.4082x over previous
//
#include <hip/hip_runtime.h>
#include <hip/hip_bf16.h>

#define BATCH 4096
#define NTHR 512

typedef __attribute__((ext_vector_type(8))) short bf16x8;
typedef __attribute__((ext_vector_type(4))) float f32x4;
typedef __attribute__((ext_vector_type(4))) short short4v;

// CK-style barrier: drain LDS only, leave global prefetches in flight
#define BAR() asm volatile("s_waitcnt lgkmcnt(0)\n\ts_barrier" ::: "memory")

// dh-sorted packing: group g (= degree) has cnt(g) units, prefix off1(g)
__host__ __device__ __forceinline__ int off1(int g) { return (g <= 16) ? 17 * g : 16 * g + 16; }
__host__ __device__ __forceinline__ int cntg(int g) { return (g < 16) ? 17 : 16; }
__host__ __device__ __forceinline__ int unitOf(int p) {
    int gp, jp;
    if (p < 272) { gp = p / 17; jp = p - gp * 17; }
    else         { gp = (p >> 4) - 1; jp = p & 15; }
    return gp + 63 * jp;
}
__device__ __forceinline__ short f2bf(float f) {
    __hip_bfloat16 h = __float2bfloat16(f);
    return *reinterpret_cast<short*>(&h);
}

// ---------------- prep6: LDS-staged coalesced packing (512 thr) — unchanged ----------------
__global__ void prep6(const float* __restrict__ W0, const float* __restrict__ b0,
                      const float* __restrict__ W1, const float* __restrict__ b1,
                      const float* __restrict__ W2,
                      short* __restrict__ W1f, short* __restrict__ W2f,
                      short* __restrict__ W0f, float* __restrict__ b1p) {
    __shared__ short ws[16][1024];
    const int b = blockIdx.x, t = threadIdx.x;
    if (b < 72) {
        const bool isW1 = (b < 64);
        const int n = t >> 5;                 // staged slot 0..15
        int u;
        if (isW1) u = unitOf(b * 16 + n);
        else { const int c = b - 64; u = (n & 1) ? (64 + c * 8 + (n >> 1)) : (c * 8 + (n >> 1)); }
        const float* src = isW1 ? (W1 + (long)u * 1024) : (W2 + (long)u * 1024);
        const int c0 = (t & 31) * 4;
#pragma unroll
        for (int j = 0; j < 8; ++j) {
            int c = c0 + j * 128;
            float4 v = *(const float4*)&src[c];
            short4v sv;
            sv[0] = f2bf(v.x); sv[1] = f2bf(v.y); sv[2] = f2bf(v.z); sv[3] = f2bf(v.w);
            *(short4v*)&ws[n][c] = sv;
        }
        __syncthreads();
#pragma unroll 1
        for (int it = 0; it < 8; ++it) {
            int v = t + it * 512;
            if (v < 4032) {
                int g = v >> 6, lane2 = v & 63;
                int nn = lane2 & 15, aq2 = lane2 >> 4;
                bf16x8 pk;
#pragma unroll
                for (int e = 0; e < 8; ++e) {
                    int k = aq2 * 8 + e;
                    pk[e] = (k < cntg(g)) ? ws[nn][g + 63 * k] : (short)0;
                }
                if (isW1) *(bf16x8*)&W1f[(((long)g * 64 + b) * 64 + lane2) * 8] = pk;
                else      *(bf16x8*)&W2f[(((long)g * 8 + (b - 64)) * 64 + lane2) * 8] = pk;
            }
        }
    } else if (b < 88) {
        const int bb = b - 72;
#pragma unroll 1
        for (int j = 0; j < 16; ++j) {
            int q = t + j * 512;
            if (q < 8064) {
                int idx = bb * 8064 + q;
                int g = idx >> 11, rem = idx & 2047;
                int n2 = rem >> 10, kt = (rem >> 9) & 1, lane2 = (rem >> 3) & 63, e = rem & 7;
                int sl = n2 * 16 + (lane2 & 15);
                int kp = kt * 32 + ((lane2 >> 4) << 3) + e;
                float val = 0.f;
                if (sl < cntg(g)) {
                    int u = unitOf(off1(g) + sl);
                    if (kp == 0) val = b0[u];
                    else if (kp - 1 <= g) val = W0[u * 64 + kp - 1];
                }
                W0f[idx] = f2bf(val);
            }
        }
    } else {
        for (int p = t; p < 1024; p += 512) b1p[p] = b1[unitOf(p)];
    }
}

// ---------------- made8: made6 verbatim, but 8 rows/block x 512 blocks ----------------
// made6 counter signature: MfmaUtil 3.9%, VALUBusy 13.6%, Occupancy 22% (ONE 8-wave
// block/CU) -> latency/serialization-bound on the 64-step chain. Fix: 2 co-resident
// blocks per CU (LDS 14.3KB*2, VGPR 104 -> 4 waves/EU) so one block's barrier-idle
// cycles are filled by the other's work. Rows 8..15 of the MFMA tile are zero-fed and
// never stored (MFMA row independence keeps them contained). Inner loop untouched.
__global__ __launch_bounds__(NTHR, 2) void made8(
    const float* __restrict__ uin, const float* __restrict__ b2,
    const short* __restrict__ W1f, const short* __restrict__ W2f,
    const short* __restrict__ W0f, const float* __restrict__ b1p,
    float* __restrict__ out) {

    __shared__ __align__(16) short h1g[16][40];   // group-g h1, [m][j], K-pad zeroed
    __shared__ __align__(16) short h2g[16][40];   // group-g h2, [m][j]
    __shared__ __align__(16) short xhist[16][80]; // [m][k']: k'=0 -> 1.0 (bias), k'=i+1 -> x_i
    __shared__ __align__(16) float uT[64][16];    // uT[i][m]
    __shared__ __align__(16) float xLs[16][68];   // staged x for final store
    __shared__ float ldjpart[8][16];

    const int t = threadIdx.x, lane = t & 63, wv = t >> 6;
    const int n = lane & 15, aq = lane >> 4;
    const int rowbase = blockIdx.x * 8;           // 8 valid rows per block

    {   // zero h1g/h2g/xhist (K pads must stay 0)
        int* z1 = (int*)&h1g[0][0];
        for (int idx = t; idx < 16 * 40 / 2; idx += NTHR) z1[idx] = 0;
        int* z2 = (int*)&h2g[0][0];
        for (int idx = t; idx < 16 * 40 / 2; idx += NTHR) z2[idx] = 0;
        int* z3 = (int*)&xhist[0][0];
        for (int idx = t; idx < 16 * 80 / 2; idx += NTHR) z3[idx] = 0;
    }
    if (t < 128) {            // rows 0..7: real data
        int r = t >> 4, c0 = (t & 15) * 4;
        float4 v = *(const float4*)&uin[(long)(rowbase + r) * 64 + c0];
        uT[c0 + 0][r] = v.x; uT[c0 + 1][r] = v.y; uT[c0 + 2][r] = v.z; uT[c0 + 3][r] = v.w;
    } else if (t < 256) {     // rows 8..15: zero-fill (keeps garbage/NaN out of the tile)
        int r = t >> 4, c0 = (t & 15) * 4;
        uT[c0 + 0][r] = 0.f; uT[c0 + 1][r] = 0.f; uT[c0 + 2][r] = 0.f; uT[c0 + 3][r] = 0.f;
    }

    // acc2: strided tile ownership (wave wv owns tiles wv+8s), b1 folded in
    f32x4 acc2[8];
#pragma unroll
    for (int s = 0; s < 8; ++s) {
        float bb = b1p[(wv + 8 * s) * 16 + n];
        acc2[s] = (f32x4){bb, bb, bb, bb};
    }
    // zacc: packed z col pc = wv*16+n (orig r = (pc>>1)+64*(pc&1)), b2 folded in
    f32x4 zacc;
    {
        int pc = wv * 16 + n;
        float bz = b2[(pc >> 1) + 64 * (pc & 1)];
        zacc = (f32x4){bz, bz, bz, bz};
    }

    // prefetch: W1f/W2f distance-2 (E/O sets); W0f per-publisher-wave distance-1
    bf16x8 w1fE[8], w1fO[8], w2fE, w2fO, w0f0, w0f1, w0f2;
#pragma unroll
    for (int s = 0; s < 8; ++s) {
        const int tile = wv + 8 * s;
        w1fO[s] = *(const bf16x8*)&W1f[(((long)0 * 64 + tile) * 64 + lane) * 8];
        w1fE[s] = *(const bf16x8*)&W1f[(((long)1 * 64 + tile) * 64 + lane) * 8];
    }
    w2fO = *(const bf16x8*)&W2f[(((long)0 * 8 + wv) * 64 + lane) * 8];
    w2fE = *(const bf16x8*)&W2f[(((long)1 * 8 + wv) * 64 + lane) * 8];
    {
        const long gb = 8 * wv;   // first group this wave will publish (<= 56)
        w0f0 = *(const bf16x8*)&W0f[((gb * 4 + 0) * 64 + lane) * 8];
        w0f1 = *(const bf16x8*)&W0f[((gb * 4 + 1) * 64 + lane) * 8];
        w0f2 = *(const bf16x8*)&W0f[((gb * 4 + 2) * 64 + lane) * 8];
    }

    f32x4 ldjacc = {0.f, 0.f, 0.f, 0.f};
    BAR();
    if (t < 16) xhist[t][0] = (short)0x3F80;   // bias column = 1.0 (wave 0; same-wave use in Q(0))
    float ureg[4];
#pragma unroll
    for (int r = 0; r < 4; ++r) ureg[r] = uT[8 * wv + (n >> 1)][aq * 4 + r];

    auto body = [&](int i, bf16x8* w1fS, bf16x8& w2fS) {
        const int g = i - 1;
        // ===== P: bulk acc2 += h1[g]*W1 (live tiles), owners finalize h2[g] =====
        if (g >= 0) {
            const int og = off1(g), cg = cntg(g);
            const int tf0 = og >> 4, tfl = (og + cg - 1) >> 4;
            const int s0 = (tf0 > wv) ? ((tf0 - wv + 7) >> 3) : 0;
            if (s0 < 8) {
                const bf16x8 af = *(const bf16x8*)&h1g[n][aq * 8];
#pragma unroll
                for (int s = 0; s < 8; ++s)
                    if (s >= s0)
                        acc2[s] = __builtin_amdgcn_mfma_f32_16x16x32_bf16(af, w1fS[s], acc2[s], 0, 0, 0);
            }
            {   // prefetch W1f group i+1 into this parity set (consumed P(i+2))
                const int gp = (i + 1 < 63) ? (i + 1) : 62;
                const int tf0p = off1(gp) >> 4;
                const int s0p = (tf0p > wv) ? ((tf0p - wv + 7) >> 3) : 0;
#pragma unroll
                for (int s = 0; s < 8; ++s)
                    if (s >= s0p)
                        w1fS[s] = *(const bf16x8*)&W1f[(((long)gp * 64 + (wv + 8 * s)) * 64 + lane) * 8];
            }
            if (wv == (tf0 & 7)) {            // owner-direct finalize (strided map: s = T>>3)
                const int sT = tf0 >> 3;
                const int j = tf0 * 16 + n - og;
                if (j >= 0 && j < cg) {
#pragma unroll
                    for (int r = 0; r < 4; ++r) {
                        float v = acc2[sT][r];
                        h2g[aq * 4 + r][j] = f2bf(v > 0.f ? v : 0.f);
                    }
                }
            }
            if (tfl != tf0 && wv == (tfl & 7)) {
                const int sT = tfl >> 3;
                const int j = tfl * 16 + n - og;
                if (j < cg) {
#pragma unroll
                    for (int r = 0; r < 4; ++r) {
                        float v = acc2[sT][r];
                        h2g[aq * 4 + r][j] = f2bf(v > 0.f ? v : 0.f);
                    }
                }
            }
            if (g == 16 && wv == 0 && n == 0) {   // first 16-wide group: clear stale col 16
#pragma unroll
                for (int r = 0; r < 4; ++r) h2g[aq * 4 + r][16] = 0;
            }
        }
        BAR();   // h2g visible
        // ===== Q: all waves zacc += h2[g]*W2; publisher: x_i then h1[group i] =====
        if (g >= 0) {
            const bf16x8 af3 = *(const bf16x8*)&h2g[n][aq * 8];
            zacc = __builtin_amdgcn_mfma_f32_16x16x32_bf16(af3, w2fS, zacc, 0, 0, 0);
            const int gp = (i + 1 < 63) ? (i + 1) : 62;
            w2fS = *(const bf16x8*)&W2f[(((long)gp * 8 + wv) * 64 + lane) * 8];
        }
        if (wv == (i >> 3)) {
            const int n0 = 2 * (i & 7);       // packed col 2i = mu, 2i+1 = sigma
            f32x4 sgv;
#pragma unroll
            for (int r = 0; r < 4; ++r) sgv[r] = __shfl_xor(zacc[r], 1);
            if (n == n0) {
#pragma unroll
                for (int r = 0; r < 4; ++r) {
                    const float sg = sgv[r], mu = zacc[r];
                    const float x = ureg[r] * __expf(sg) + mu;
                    ldjacc[r] += sg;
                    const int m = aq * 4 + r;
                    xLs[m][i] = x;
                    if (i < 63) xhist[m][i + 1] = f2bf(x);
                }
            }
            if (i < 63) {   // h1[group i] from xhist (same-wave writes; lgkmcnt only)
                const bf16x8 ax0 = *(const bf16x8*)&xhist[n][aq * 8];
                f32x4 d0 = {0.f, 0.f, 0.f, 0.f};
                d0 = __builtin_amdgcn_mfma_f32_16x16x32_bf16(ax0, w0f0, d0, 0, 0, 0);
                if (i >= 31) {                // K extent i+2 > 32: second k-tile
                    const bf16x8 ax1 = *(const bf16x8*)&xhist[n][32 + aq * 8];
                    d0 = __builtin_amdgcn_mfma_f32_16x16x32_bf16(ax1, w0f1, d0, 0, 0, 0);
                }
                f32x4 d1 = {0.f, 0.f, 0.f, 0.f};
                if (i < 16)                   // 17-wide groups: col-16 tile (extent <=17, 1 k-tile)
                    d1 = __builtin_amdgcn_mfma_f32_16x16x32_bf16(ax0, w0f2, d1, 0, 0, 0);
#pragma unroll
                for (int r = 0; r < 4; ++r) {
                    float v = d0[r];
                    h1g[aq * 4 + r][n] = f2bf(v > 0.f ? v : 0.f);
                }
                if (n == 0) {
#pragma unroll
                    for (int r = 0; r < 4; ++r) {
                        float v = (i < 16) ? (d1[r] > 0.f ? d1[r] : 0.f) : 0.f;
                        h1g[aq * 4 + r][16] = f2bf(v);
                    }
                }
                if (i + 1 < 63 && ((i + 1) >> 3) == wv) {   // next group still ours: prefetch
                    const long gb = i + 1;
                    w0f0 = *(const bf16x8*)&W0f[((gb * 4 + 0) * 64 + lane) * 8];
                    w0f1 = *(const bf16x8*)&W0f[((gb * 4 + 1) * 64 + lane) * 8];
                    w0f2 = *(const bf16x8*)&W0f[((gb * 4 + 2) * 64 + lane) * 8];
                }
            }
        }
        BAR();   // h1g / xhist / xLs visible
    };

#pragma unroll 1
    for (int i = 0; i < 64; i += 2) {
        body(i, w1fE, w2fE);
        body(i + 1, w1fO, w2fO);
    }

    // ldj: publisher lanes are even n; xor-reduce over even lanes, then across waves
#pragma unroll
    for (int r = 0; r < 4; ++r) {
        float v = ldjacc[r];
        v += __shfl_xor(v, 2);
        v += __shfl_xor(v, 4);
        v += __shfl_xor(v, 8);
        if (n == 0) ldjpart[wv][aq * 4 + r] = v;
    }
    BAR();

    if (t < 128) {            // store 8 valid rows
        int r = t >> 4, c = (t & 15) * 4;
        float4 v;
        v.x = xLs[r][c]; v.y = xLs[r][c + 1]; v.z = xLs[r][c + 2]; v.w = xLs[r][c + 3];
        *(float4*)&out[(long)(rowbase + r) * 64 + c] = v;
    }
    if (t < 8) {
        float s = 0.f;
#pragma unroll
        for (int w = 0; w < 8; ++w) s += ldjpart[w][t];
        out[(long)BATCH * 64 + rowbase + t] = s;
    }
}

extern "C" void kernel_launch(void* const* d_in, const int* in_sizes, int n_in,
                              void* d_out, int out_size, void* d_ws, size_t ws_size,
                              hipStream_t stream) {
    (void)in_sizes; (void)n_in; (void)out_size; (void)ws_size;
    const float* u  = (const float*)d_in[0];
    const float* W0 = (const float*)d_in[1];
    const float* b0 = (const float*)d_in[2];
    const float* W1 = (const float*)d_in[3];
    const float* b1 = (const float*)d_in[4];
    const float* W2 = (const float*)d_in[5];
    const float* b2 = (const float*)d_in[6];
    float* out = (float*)d_out;

    // d_ws layout (bytes): W1f 4,128,768 | W2f 516,096 | W0f 258,048 | b1p 4,096
    short* W1f = (short*)d_ws;
    short* W2f = (short*)((char*)d_ws + 4128768);
    short* W0f = (short*)((char*)d_ws + 4128768 + 516096);
    float* b1p = (float*)((char*)d_ws + 4128768 + 516096 + 258048);

    prep6<<<dim3(89), dim3(512), 0, stream>>>(W0, b0, W1, b1, W2, W1f, W2f, W0f, b1p);
    made8<<<dim3(BATCH / 8), dim3(NTHR), 0, stream>>>(u, b2, W1f, W2f, W0f, b1p, out);
}

// Round 6
// 215.835 us; speedup vs baseline: 2.0631x; 1.2271x over previous
//
#include <hip/hip_runtime.h>
#include <hip/hip_bf16.h>

#define BATCH 4096
#define NTHR 512

typedef __attribute__((ext_vector_type(8))) short bf16x8;
typedef __attribute__((ext_vector_type(4))) float f32x4;
typedef __attribute__((ext_vector_type(4))) short short4v;

// CK-style barrier: drain LDS only, leave global prefetches in flight
#define BAR() asm volatile("s_waitcnt lgkmcnt(0)\n\ts_barrier" ::: "memory")

// dh-sorted packing: group g (= degree) has cnt(g) units, prefix off1(g)
__host__ __device__ __forceinline__ int off1(int g) { return (g <= 16) ? 17 * g : 16 * g + 16; }
__host__ __device__ __forceinline__ int cntg(int g) { return (g < 16) ? 17 : 16; }
__host__ __device__ __forceinline__ int unitOf(int p) {
    int gp, jp;
    if (p < 272) { gp = p / 17; jp = p - gp * 17; }
    else         { gp = (p >> 4) - 1; jp = p & 15; }
    return gp + 63 * jp;
}
__device__ __forceinline__ short f2bf(float f) {
    __hip_bfloat16 h = __float2bfloat16(f);
    return *reinterpret_cast<short*>(&h);
}
__device__ __forceinline__ float bfrnd(float f) {
    __hip_bfloat16 h = __float2bfloat16(f);
    return __bfloat162float(h);
}

// ---------------- prep6: LDS-staged coalesced packing (512 thr) — unchanged ----------------
__global__ void prep6(const float* __restrict__ W0, const float* __restrict__ b0,
                      const float* __restrict__ W1, const float* __restrict__ b1,
                      const float* __restrict__ W2,
                      short* __restrict__ W1f, short* __restrict__ W2f,
                      short* __restrict__ W0f, float* __restrict__ b1p) {
    __shared__ short ws[16][1024];
    const int b = blockIdx.x, t = threadIdx.x;
    if (b < 72) {
        const bool isW1 = (b < 64);
        const int n = t >> 5;                 // staged slot 0..15
        int u;
        if (isW1) u = unitOf(b * 16 + n);
        else { const int c = b - 64; u = (n & 1) ? (64 + c * 8 + (n >> 1)) : (c * 8 + (n >> 1)); }
        const float* src = isW1 ? (W1 + (long)u * 1024) : (W2 + (long)u * 1024);
        const int c0 = (t & 31) * 4;
#pragma unroll
        for (int j = 0; j < 8; ++j) {
            int c = c0 + j * 128;
            float4 v = *(const float4*)&src[c];
            short4v sv;
            sv[0] = f2bf(v.x); sv[1] = f2bf(v.y); sv[2] = f2bf(v.z); sv[3] = f2bf(v.w);
            *(short4v*)&ws[n][c] = sv;
        }
        __syncthreads();
#pragma unroll 1
        for (int it = 0; it < 8; ++it) {
            int v = t + it * 512;
            if (v < 4032) {
                int g = v >> 6, lane2 = v & 63;
                int nn = lane2 & 15, aq2 = lane2 >> 4;
                bf16x8 pk;
#pragma unroll
                for (int e = 0; e < 8; ++e) {
                    int k = aq2 * 8 + e;
                    pk[e] = (k < cntg(g)) ? ws[nn][g + 63 * k] : (short)0;
                }
                if (isW1) *(bf16x8*)&W1f[(((long)g * 64 + b) * 64 + lane2) * 8] = pk;
                else      *(bf16x8*)&W2f[(((long)g * 8 + (b - 64)) * 64 + lane2) * 8] = pk;
            }
        }
    } else if (b < 88) {
        const int bb = b - 72;
#pragma unroll 1
        for (int j = 0; j < 16; ++j) {
            int q = t + j * 512;
            if (q < 8064) {
                int idx = bb * 8064 + q;
                int g = idx >> 11, rem = idx & 2047;
                int n2 = rem >> 10, kt = (rem >> 9) & 1, lane2 = (rem >> 3) & 63, e = rem & 7;
                int sl = n2 * 16 + (lane2 & 15);
                int kp = kt * 32 + ((lane2 >> 4) << 3) + e;
                float val = 0.f;
                if (sl < cntg(g)) {
                    int u = unitOf(off1(g) + sl);
                    if (kp == 0) val = b0[u];
                    else if (kp - 1 <= g) val = W0[u * 64 + kp - 1];
                }
                W0f[idx] = f2bf(val);
            }
        }
    } else {
        for (int p = t; p < 1024; p += 512) b1p[p] = b1[unitOf(p)];
    }
}

// ---------------- made9: made6 + early-partial-h1 MFMA + rank-1 finish + publisher setprio ----
// made6 interval = ~1975cy; the Q-phase publisher tail (xhist write -> lgkm -> ds_read ->
// 2-3 dependent MFMAs) sits at the END of the serial chain. Fix (numerics proven by the
// made7 family, absmax unchanged across 4 passes): read xhist BEFORE x_i is written (col
// i+1 still zero), issue the h1 MFMAs early so they overlap the zacc->shfl->expf chain,
// then finish with a rank-1 register update h = d0p + x_i * W0col via broadcast shuffle.
// Rank-1 coeffs ride in two rotating scalars prefetched one step ahead (no arrays).
// Everything else (P phase, prefetch scheme, barriers) is byte-identical to made6.
__global__ __launch_bounds__(NTHR, 2) void made9(
    const float* __restrict__ uin, const float* __restrict__ b2,
    const float* __restrict__ W0,
    const short* __restrict__ W1f, const short* __restrict__ W2f,
    const short* __restrict__ W0f, const float* __restrict__ b1p,
    float* __restrict__ out) {

    __shared__ __align__(16) short h1g[16][40];   // group-g h1, [m][j], K-pad zeroed
    __shared__ __align__(16) short h2g[16][40];   // group-g h2, [m][j]
    __shared__ __align__(16) short xhist[16][80]; // [m][k']: k'=0 -> 1.0 (bias), k'=i+1 -> x_i
    __shared__ __align__(16) float uT[64][16];    // uT[i][m]
    __shared__ __align__(16) float xLs[16][68];   // staged x for final store
    __shared__ float ldjpart[8][16];

    const int t = threadIdx.x, lane = t & 63, wv = t >> 6;
    const int n = lane & 15, aq = lane >> 4;
    const int rowbase = blockIdx.x * 16;

    {   // zero h1g/h2g/xhist (K pads must stay 0)
        int* z1 = (int*)&h1g[0][0];
        for (int idx = t; idx < 16 * 40 / 2; idx += NTHR) z1[idx] = 0;
        int* z2 = (int*)&h2g[0][0];
        for (int idx = t; idx < 16 * 40 / 2; idx += NTHR) z2[idx] = 0;
        int* z3 = (int*)&xhist[0][0];
        for (int idx = t; idx < 16 * 80 / 2; idx += NTHR) z3[idx] = 0;
    }
    if (t < 256) {
        int r = t >> 4, c0 = (t & 15) * 4;
        float4 v = *(const float4*)&uin[(long)(rowbase + r) * 64 + c0];
        uT[c0 + 0][r] = v.x; uT[c0 + 1][r] = v.y; uT[c0 + 2][r] = v.z; uT[c0 + 3][r] = v.w;
    }

    // acc2: strided tile ownership (wave wv owns tiles wv+8s), b1 folded in
    f32x4 acc2[8];
#pragma unroll
    for (int s = 0; s < 8; ++s) {
        float bb = b1p[(wv + 8 * s) * 16 + n];
        acc2[s] = (f32x4){bb, bb, bb, bb};
    }
    // zacc: packed z col pc = wv*16+n (orig r = (pc>>1)+64*(pc&1)), b2 folded in
    f32x4 zacc;
    {
        int pc = wv * 16 + n;
        float bz = b2[(pc >> 1) + 64 * (pc & 1)];
        zacc = (f32x4){bz, bz, bz, bz};
    }

    // prefetch: W1f/W2f distance-2 (E/O sets); W0f per-publisher-wave distance-1
    bf16x8 w1fE[8], w1fO[8], w2fE, w2fO, w0f0, w0f1, w0f2;
#pragma unroll
    for (int s = 0; s < 8; ++s) {
        const int tile = wv + 8 * s;
        w1fO[s] = *(const bf16x8*)&W1f[(((long)0 * 64 + tile) * 64 + lane) * 8];
        w1fE[s] = *(const bf16x8*)&W1f[(((long)1 * 64 + tile) * 64 + lane) * 8];
    }
    w2fO = *(const bf16x8*)&W2f[(((long)0 * 8 + wv) * 64 + lane) * 8];
    w2fE = *(const bf16x8*)&W2f[(((long)1 * 8 + wv) * 64 + lane) * 8];
    {
        const long gb = 8 * wv;   // first group this wave will publish (<= 56)
        w0f0 = *(const bf16x8*)&W0f[((gb * 4 + 0) * 64 + lane) * 8];
        w0f1 = *(const bf16x8*)&W0f[((gb * 4 + 1) * 64 + lane) * 8];
        w0f2 = *(const bf16x8*)&W0f[((gb * 4 + 2) * 64 + lane) * 8];
    }
    // rank-1 coefficients for this wave's FIRST publisher step (i0 = 8*wv <= 56 < 63);
    // subsequent steps prefetch one ahead into the same rotating scalars.
    float w0dCur, w0d16Cur;
    {
        const int i0 = 8 * wv;
        w0dCur = bfrnd(W0[unitOf(off1(i0) + n) * 64 + i0]);
        w0d16Cur = (i0 < 16) ? bfrnd(W0[unitOf(off1(i0) + 16) * 64 + i0]) : 0.f;
    }

    f32x4 ldjacc = {0.f, 0.f, 0.f, 0.f};
    BAR();
    if (t < 16) xhist[t][0] = (short)0x3F80;   // bias column = 1.0 (wave 0; same-wave use in Q(0))
    float ureg[4];
#pragma unroll
    for (int r = 0; r < 4; ++r) ureg[r] = uT[8 * wv + (n >> 1)][aq * 4 + r];

    auto body = [&](int i, bf16x8* w1fS, bf16x8& w2fS) {
        const int g = i - 1;
        // ===== P: bulk acc2 += h1[g]*W1 (live tiles), owners finalize h2[g] =====
        if (g >= 0) {
            const int og = off1(g), cg = cntg(g);
            const int tf0 = og >> 4, tfl = (og + cg - 1) >> 4;
            const int s0 = (tf0 > wv) ? ((tf0 - wv + 7) >> 3) : 0;
            if (s0 < 8) {
                const bf16x8 af = *(const bf16x8*)&h1g[n][aq * 8];
#pragma unroll
                for (int s = 0; s < 8; ++s)
                    if (s >= s0)
                        acc2[s] = __builtin_amdgcn_mfma_f32_16x16x32_bf16(af, w1fS[s], acc2[s], 0, 0, 0);
            }
            {   // prefetch W1f group i+1 into this parity set (consumed P(i+2))
                const int gp = (i + 1 < 63) ? (i + 1) : 62;
                const int tf0p = off1(gp) >> 4;
                const int s0p = (tf0p > wv) ? ((tf0p - wv + 7) >> 3) : 0;
#pragma unroll
                for (int s = 0; s < 8; ++s)
                    if (s >= s0p)
                        w1fS[s] = *(const bf16x8*)&W1f[(((long)gp * 64 + (wv + 8 * s)) * 64 + lane) * 8];
            }
            if (wv == (tf0 & 7)) {            // owner-direct finalize (strided map: s = T>>3)
                const int sT = tf0 >> 3;
                const int j = tf0 * 16 + n - og;
                if (j >= 0 && j < cg) {
#pragma unroll
                    for (int r = 0; r < 4; ++r) {
                        float v = acc2[sT][r];
                        h2g[aq * 4 + r][j] = f2bf(v > 0.f ? v : 0.f);
                    }
                }
            }
            if (tfl != tf0 && wv == (tfl & 7)) {
                const int sT = tfl >> 3;
                const int j = tfl * 16 + n - og;
                if (j < cg) {
#pragma unroll
                    for (int r = 0; r < 4; ++r) {
                        float v = acc2[sT][r];
                        h2g[aq * 4 + r][j] = f2bf(v > 0.f ? v : 0.f);
                    }
                }
            }
            if (g == 16 && wv == 0 && n == 0) {   // first 16-wide group: clear stale col 16
#pragma unroll
                for (int r = 0; r < 4; ++r) h2g[aq * 4 + r][16] = 0;
            }
        }
        BAR();   // h2g visible
        // ===== Q: all waves zacc += h2[g]*W2; publisher: x_i then h1[group i] =====
        if (g >= 0) {
            const bf16x8 af3 = *(const bf16x8*)&h2g[n][aq * 8];
            zacc = __builtin_amdgcn_mfma_f32_16x16x32_bf16(af3, w2fS, zacc, 0, 0, 0);
            const int gp = (i + 1 < 63) ? (i + 1) : 62;
            w2fS = *(const bf16x8*)&W2f[(((long)gp * 8 + wv) * 64 + lane) * 8];
        }
        if (wv == (i >> 3)) {
            __builtin_amdgcn_s_setprio(1);
            const int n0 = 2 * (i & 7);       // packed col 2i = mu, 2i+1 = sigma
            const bool doH1 = (i < 63);
            // EARLY partial h1[i] MFMAs: xhist read PRECEDES the x_i write (col i+1 is
            // still zero), so these overlap the zacc->shfl->expf extraction chain and
            // the fresh column is added by the rank-1 update below.
            f32x4 d0p = {0.f, 0.f, 0.f, 0.f}, d1p = {0.f, 0.f, 0.f, 0.f};
            if (doH1) {
                const bf16x8 ax0 = *(const bf16x8*)&xhist[n][aq * 8];
                d0p = __builtin_amdgcn_mfma_f32_16x16x32_bf16(ax0, w0f0, d0p, 0, 0, 0);
                if (i >= 31) {
                    const bf16x8 ax1 = *(const bf16x8*)&xhist[n][32 + aq * 8];
                    d0p = __builtin_amdgcn_mfma_f32_16x16x32_bf16(ax1, w0f1, d0p, 0, 0, 0);
                }
                if (i < 16)
                    d1p = __builtin_amdgcn_mfma_f32_16x16x32_bf16(ax0, w0f2, d1p, 0, 0, 0);
            }
            f32x4 sgv;
#pragma unroll
            for (int r = 0; r < 4; ++r) sgv[r] = __shfl_xor(zacc[r], 1);
            f32x4 xv;
            if (n == n0) {
#pragma unroll
                for (int r = 0; r < 4; ++r) {
                    const float sg = sgv[r], mu = zacc[r];
                    const float x = ureg[r] * __expf(sg) + mu;
                    ldjacc[r] += sg;
                    xv[r] = x;
                    const int m = aq * 4 + r;
                    xLs[m][i] = x;
                    if (doH1) xhist[m][i + 1] = f2bf(x);
                }
            }
            if (doH1) {   // rank-1 finish + publish h1[i]
#pragma unroll
                for (int r = 0; r < 4; ++r) {
                    const float xb = bfrnd(__shfl(xv[r], (lane & 48) | n0));
                    const float h = d0p[r] + xb * w0dCur;
                    h1g[aq * 4 + r][n] = f2bf(h > 0.f ? h : 0.f);
                    if (n == 0) {
                        const float h16 = (i < 16) ? (d1p[r] + xb * w0d16Cur) : 0.f;
                        h1g[aq * 4 + r][16] = f2bf(h16 > 0.f ? h16 : 0.f);
                    }
                }
                if ((i & 7) < 7) {   // coeffs for step i+1 (same wave publishes it)
                    const int i2 = i + 1;
                    if (i2 < 63) {
                        w0dCur = bfrnd(W0[unitOf(off1(i2) + n) * 64 + i2]);
                        w0d16Cur = (i2 < 16) ? bfrnd(W0[unitOf(off1(i2) + 16) * 64 + i2]) : 0.f;
                    }
                }
                if (i + 1 < 63 && ((i + 1) >> 3) == wv) {   // next group still ours: prefetch frags
                    const long gb = i + 1;
                    w0f0 = *(const bf16x8*)&W0f[((gb * 4 + 0) * 64 + lane) * 8];
                    w0f1 = *(const bf16x8*)&W0f[((gb * 4 + 1) * 64 + lane) * 8];
                    w0f2 = *(const bf16x8*)&W0f[((gb * 4 + 2) * 64 + lane) * 8];
                }
            }
            __builtin_amdgcn_s_setprio(0);
        }
        BAR();   // h1g / xhist / xLs visible
    };

#pragma unroll 1
    for (int i = 0; i < 64; i += 2) {
        body(i, w1fE, w2fE);
        body(i + 1, w1fO, w2fO);
    }

    // ldj: publisher lanes are even n; xor-reduce over even lanes, then across waves
#pragma unroll
    for (int r = 0; r < 4; ++r) {
        float v = ldjacc[r];
        v += __shfl_xor(v, 2);
        v += __shfl_xor(v, 4);
        v += __shfl_xor(v, 8);
        if (n == 0) ldjpart[wv][aq * 4 + r] = v;
    }
    BAR();

    if (t < 256) {
        int r = t >> 4, c = (t & 15) * 4;
        float4 v;
        v.x = xLs[r][c]; v.y = xLs[r][c + 1]; v.z = xLs[r][c + 2]; v.w = xLs[r][c + 3];
        *(float4*)&out[(long)(rowbase + r) * 64 + c] = v;
    }
    if (t < 16) {
        float s = 0.f;
#pragma unroll
        for (int w = 0; w < 8; ++w) s += ldjpart[w][t];
        out[(long)BATCH * 64 + rowbase + t] = s;
    }
}

extern "C" void kernel_launch(void* const* d_in, const int* in_sizes, int n_in,
                              void* d_out, int out_size, void* d_ws, size_t ws_size,
                              hipStream_t stream) {
    (void)in_sizes; (void)n_in; (void)out_size; (void)ws_size;
    const float* u  = (const float*)d_in[0];
    const float* W0 = (const float*)d_in[1];
    const float* b0 = (const float*)d_in[2];
    const float* W1 = (const float*)d_in[3];
    const float* b1 = (const float*)d_in[4];
    const float* W2 = (const float*)d_in[5];
    const float* b2 = (const float*)d_in[6];
    float* out = (float*)d_out;

    // d_ws layout (bytes): W1f 4,128,768 | W2f 516,096 | W0f 258,048 | b1p 4,096
    short* W1f = (short*)d_ws;
    short* W2f = (short*)((char*)d_ws + 4128768);
    short* W0f = (short*)((char*)d_ws + 4128768 + 516096);
    float* b1p = (float*)((char*)d_ws + 4128768 + 516096 + 258048);

    prep6<<<dim3(89), dim3(512), 0, stream>>>(W0, b0, W1, b1, W2, W1f, W2f, W0f, b1p);
    made9<<<dim3(BATCH / 16), dim3(NTHR), 0, stream>>>(u, b2, W0, W1f, W2f, W0f, b1p, out);
}

// Round 7
// 177.628 us; speedup vs baseline: 2.5069x; 1.2151x over previous
//
#include <hip/hip_runtime.h>
#include <hip/hip_bf16.h>

#define BATCH 4096
#define NTHR 512

typedef __attribute__((ext_vector_type(8))) short bf16x8;
typedef __attribute__((ext_vector_type(4))) float f32x4;
typedef __attribute__((ext_vector_type(4))) short short4v;

// CK-style barrier: drain LDS only, leave global prefetches in flight
#define BAR() asm volatile("s_waitcnt lgkmcnt(0)\n\ts_barrier" ::: "memory")

// dh-sorted packing: group g (= degree) has cnt(g) units, prefix off1(g)
__host__ __device__ __forceinline__ int off1(int g) { return (g <= 16) ? 17 * g : 16 * g + 16; }
__host__ __device__ __forceinline__ int cntg(int g) { return (g < 16) ? 17 : 16; }
__host__ __device__ __forceinline__ int unitOf(int p) {
    int gp, jp;
    if (p < 272) { gp = p / 17; jp = p - gp * 17; }
    else         { gp = (p >> 4) - 1; jp = p & 15; }
    return gp + 63 * jp;
}
__device__ __forceinline__ short f2bf(float f) {
    __hip_bfloat16 h = __float2bfloat16(f);
    return *reinterpret_cast<short*>(&h);
}

// ---------------- prep7: prep6 reworked for parallelism + bank conflicts ----------------
// prep6 defects: 89 blocks (35% of 256 CUs) and a 16-way LDS bank conflict on the
// gather ws[nn][g+63k] (row stride 2048B -> all rows start at bank 0; 16 lanes with
// equal aq2 hit one bank). prep7: (a) pad rows to 1028 shorts (2056B, 8B-aligned;
// bank step 2/row -> ~4-way, near-free); (b) split W1 into 64 tiles x 4 group-chunks
// (256 blocks) and W2 into 8 units-sets x 4 chunks (32 blocks); W0 16 blocks; b1p 1.
// Grid 305, full GPU, 4x less gather work per block. Output layout & math bit-identical.
__global__ void prep7(const float* __restrict__ W0, const float* __restrict__ b0,
                      const float* __restrict__ W1, const float* __restrict__ b1,
                      const float* __restrict__ W2,
                      short* __restrict__ W1f, short* __restrict__ W2f,
                      short* __restrict__ W0f, float* __restrict__ b1p) {
    __shared__ short ws[16][1028];   // +4 shorts pad: 8B-aligned rows, 16-way -> 4-way banks
    const int b = blockIdx.x, t = threadIdx.x;
    if (b < 288) {
        const bool isW1 = (b < 256);
        const int tile = isW1 ? (b >> 2) : ((b - 256) >> 2);   // W1 tile / W2 unit-set
        const int chunk = isW1 ? (b & 3) : ((b - 256) & 3);
        const int n = t >> 5;                 // staged slot 0..15
        int u;
        if (isW1) u = unitOf(tile * 16 + n);
        else      u = (n & 1) ? (64 + tile * 8 + (n >> 1)) : (tile * 8 + (n >> 1));
        const float* src = isW1 ? (W1 + (long)u * 1024) : (W2 + (long)u * 1024);
        const int c0 = (t & 31) * 4;
#pragma unroll
        for (int j = 0; j < 8; ++j) {
            int c = c0 + j * 128;
            float4 v = *(const float4*)&src[c];
            short4v sv;
            sv[0] = f2bf(v.x); sv[1] = f2bf(v.y); sv[2] = f2bf(v.z); sv[3] = f2bf(v.w);
            *(short4v*)&ws[n][c] = sv;
        }
        __syncthreads();
        const int ng = (chunk < 3) ? 16 : 15;   // chunk 3 covers groups 48..62
#pragma unroll 1
        for (int it = 0; it < 2; ++it) {
            int v = t + it * 512;
            if (v < ng * 64) {
                int gl = chunk * 16 + (v >> 6), lane2 = v & 63;
                int nn = lane2 & 15, aq2 = lane2 >> 4;
                bf16x8 pk;
#pragma unroll
                for (int e = 0; e < 8; ++e) {
                    int k = aq2 * 8 + e;
                    pk[e] = (k < cntg(gl)) ? ws[nn][gl + 63 * k] : (short)0;
                }
                if (isW1) *(bf16x8*)&W1f[(((long)gl * 64 + tile) * 64 + lane2) * 8] = pk;
                else      *(bf16x8*)&W2f[(((long)gl * 8 + tile) * 64 + lane2) * 8] = pk;
            }
        }
    } else if (b < 304) {
        const int bb = b - 288;
#pragma unroll 1
        for (int j = 0; j < 16; ++j) {
            int q = t + j * 512;
            if (q < 8064) {
                int idx = bb * 8064 + q;
                int g = idx >> 11, rem = idx & 2047;
                int n2 = rem >> 10, kt = (rem >> 9) & 1, lane2 = (rem >> 3) & 63, e = rem & 7;
                int sl = n2 * 16 + (lane2 & 15);
                int kp = kt * 32 + ((lane2 >> 4) << 3) + e;
                float val = 0.f;
                if (sl < cntg(g)) {
                    int u = unitOf(off1(g) + sl);
                    if (kp == 0) val = b0[u];
                    else if (kp - 1 <= g) val = W0[u * 64 + kp - 1];
                }
                W0f[idx] = f2bf(val);
            }
        }
    } else {
        for (int p = t; p < 1024; p += 512) b1p[p] = b1[unitOf(p)];
    }
}

// ---------------- made6: byte-identical revert of the verified 105.4 us kernel ----------------
// Three interval-attack attempts (made7 window scheme, made8 row-split, made9 tail
// shortening) all regressed; the made6 inner loop is frozen.
__global__ __launch_bounds__(NTHR, 2) void made6(
    const float* __restrict__ uin, const float* __restrict__ b2,
    const short* __restrict__ W1f, const short* __restrict__ W2f,
    const short* __restrict__ W0f, const float* __restrict__ b1p,
    float* __restrict__ out) {

    __shared__ __align__(16) short h1g[16][40];   // group-g h1, [m][j], K-pad zeroed
    __shared__ __align__(16) short h2g[16][40];   // group-g h2, [m][j]
    __shared__ __align__(16) short xhist[16][80]; // [m][k']: k'=0 -> 1.0 (bias), k'=i+1 -> x_i
    __shared__ __align__(16) float uT[64][16];    // uT[i][m]
    __shared__ __align__(16) float xLs[16][68];   // staged x for final store
    __shared__ float ldjpart[8][16];

    const int t = threadIdx.x, lane = t & 63, wv = t >> 6;
    const int n = lane & 15, aq = lane >> 4;
    const int rowbase = blockIdx.x * 16;

    {   // zero h1g/h2g/xhist (K pads must stay 0)
        int* z1 = (int*)&h1g[0][0];
        for (int idx = t; idx < 16 * 40 / 2; idx += NTHR) z1[idx] = 0;
        int* z2 = (int*)&h2g[0][0];
        for (int idx = t; idx < 16 * 40 / 2; idx += NTHR) z2[idx] = 0;
        int* z3 = (int*)&xhist[0][0];
        for (int idx = t; idx < 16 * 80 / 2; idx += NTHR) z3[idx] = 0;
    }
    if (t < 256) {
        int r = t >> 4, c0 = (t & 15) * 4;
        float4 v = *(const float4*)&uin[(long)(rowbase + r) * 64 + c0];
        uT[c0 + 0][r] = v.x; uT[c0 + 1][r] = v.y; uT[c0 + 2][r] = v.z; uT[c0 + 3][r] = v.w;
    }

    // acc2: strided tile ownership (wave wv owns tiles wv+8s), b1 folded in
    f32x4 acc2[8];
#pragma unroll
    for (int s = 0; s < 8; ++s) {
        float bb = b1p[(wv + 8 * s) * 16 + n];
        acc2[s] = (f32x4){bb, bb, bb, bb};
    }
    // zacc: packed z col pc = wv*16+n (orig r = (pc>>1)+64*(pc&1)), b2 folded in
    f32x4 zacc;
    {
        int pc = wv * 16 + n;
        float bz = b2[(pc >> 1) + 64 * (pc & 1)];
        zacc = (f32x4){bz, bz, bz, bz};
    }

    // prefetch: W1f/W2f distance-2 (E/O sets); W0f per-publisher-wave distance-1
    bf16x8 w1fE[8], w1fO[8], w2fE, w2fO, w0f0, w0f1, w0f2;
#pragma unroll
    for (int s = 0; s < 8; ++s) {
        const int tile = wv + 8 * s;
        w1fO[s] = *(const bf16x8*)&W1f[(((long)0 * 64 + tile) * 64 + lane) * 8];
        w1fE[s] = *(const bf16x8*)&W1f[(((long)1 * 64 + tile) * 64 + lane) * 8];
    }
    w2fO = *(const bf16x8*)&W2f[(((long)0 * 8 + wv) * 64 + lane) * 8];
    w2fE = *(const bf16x8*)&W2f[(((long)1 * 8 + wv) * 64 + lane) * 8];
    {
        const long gb = 8 * wv;   // first group this wave will publish (<= 56)
        w0f0 = *(const bf16x8*)&W0f[((gb * 4 + 0) * 64 + lane) * 8];
        w0f1 = *(const bf16x8*)&W0f[((gb * 4 + 1) * 64 + lane) * 8];
        w0f2 = *(const bf16x8*)&W0f[((gb * 4 + 2) * 64 + lane) * 8];
    }

    f32x4 ldjacc = {0.f, 0.f, 0.f, 0.f};
    BAR();
    if (t < 16) xhist[t][0] = (short)0x3F80;   // bias column = 1.0 (wave 0; same-wave use in Q(0))
    float ureg[4];
#pragma unroll
    for (int r = 0; r < 4; ++r) ureg[r] = uT[8 * wv + (n >> 1)][aq * 4 + r];

    auto body = [&](int i, bf16x8* w1fS, bf16x8& w2fS) {
        const int g = i - 1;
        // ===== P: bulk acc2 += h1[g]*W1 (live tiles), owners finalize h2[g] =====
        if (g >= 0) {
            const int og = off1(g), cg = cntg(g);
            const int tf0 = og >> 4, tfl = (og + cg - 1) >> 4;
            const int s0 = (tf0 > wv) ? ((tf0 - wv + 7) >> 3) : 0;
            if (s0 < 8) {
                const bf16x8 af = *(const bf16x8*)&h1g[n][aq * 8];
#pragma unroll
                for (int s = 0; s < 8; ++s)
                    if (s >= s0)
                        acc2[s] = __builtin_amdgcn_mfma_f32_16x16x32_bf16(af, w1fS[s], acc2[s], 0, 0, 0);
            }
            {   // prefetch W1f group i+1 into this parity set (consumed P(i+2))
                const int gp = (i + 1 < 63) ? (i + 1) : 62;
                const int tf0p = off1(gp) >> 4;
                const int s0p = (tf0p > wv) ? ((tf0p - wv + 7) >> 3) : 0;
#pragma unroll
                for (int s = 0; s < 8; ++s)
                    if (s >= s0p)
                        w1fS[s] = *(const bf16x8*)&W1f[(((long)gp * 64 + (wv + 8 * s)) * 64 + lane) * 8];
            }
            if (wv == (tf0 & 7)) {            // owner-direct finalize (strided map: s = T>>3)
                const int sT = tf0 >> 3;
                const int j = tf0 * 16 + n - og;
                if (j >= 0 && j < cg) {
#pragma unroll
                    for (int r = 0; r < 4; ++r) {
                        float v = acc2[sT][r];
                        h2g[aq * 4 + r][j] = f2bf(v > 0.f ? v : 0.f);
                    }
                }
            }
            if (tfl != tf0 && wv == (tfl & 7)) {
                const int sT = tfl >> 3;
                const int j = tfl * 16 + n - og;
                if (j < cg) {
#pragma unroll
                    for (int r = 0; r < 4; ++r) {
                        float v = acc2[sT][r];
                        h2g[aq * 4 + r][j] = f2bf(v > 0.f ? v : 0.f);
                    }
                }
            }
            if (g == 16 && wv == 0 && n == 0) {   // first 16-wide group: clear stale col 16
#pragma unroll
                for (int r = 0; r < 4; ++r) h2g[aq * 4 + r][16] = 0;
            }
        }
        BAR();   // h2g visible
        // ===== Q: all waves zacc += h2[g]*W2; publisher: x_i then h1[group i] =====
        if (g >= 0) {
            const bf16x8 af3 = *(const bf16x8*)&h2g[n][aq * 8];
            zacc = __builtin_amdgcn_mfma_f32_16x16x32_bf16(af3, w2fS, zacc, 0, 0, 0);
            const int gp = (i + 1 < 63) ? (i + 1) : 62;
            w2fS = *(const bf16x8*)&W2f[(((long)gp * 8 + wv) * 64 + lane) * 8];
        }
        if (wv == (i >> 3)) {
            const int n0 = 2 * (i & 7);       // packed col 2i = mu, 2i+1 = sigma
            f32x4 sgv;
#pragma unroll
            for (int r = 0; r < 4; ++r) sgv[r] = __shfl_xor(zacc[r], 1);
            if (n == n0) {
#pragma unroll
                for (int r = 0; r < 4; ++r) {
                    const float sg = sgv[r], mu = zacc[r];
                    const float x = ureg[r] * __expf(sg) + mu;
                    ldjacc[r] += sg;
                    const int m = aq * 4 + r;
                    xLs[m][i] = x;
                    if (i < 63) xhist[m][i + 1] = f2bf(x);
                }
            }
            if (i < 63) {   // h1[group i] from xhist (same-wave writes; lgkmcnt only)
                const bf16x8 ax0 = *(const bf16x8*)&xhist[n][aq * 8];
                f32x4 d0 = {0.f, 0.f, 0.f, 0.f};
                d0 = __builtin_amdgcn_mfma_f32_16x16x32_bf16(ax0, w0f0, d0, 0, 0, 0);
                if (i >= 31) {                // K extent i+2 > 32: second k-tile
                    const bf16x8 ax1 = *(const bf16x8*)&xhist[n][32 + aq * 8];
                    d0 = __builtin_amdgcn_mfma_f32_16x16x32_bf16(ax1, w0f1, d0, 0, 0, 0);
                }
                f32x4 d1 = {0.f, 0.f, 0.f, 0.f};
                if (i < 16)                   // 17-wide groups: col-16 tile (extent <=17, 1 k-tile)
                    d1 = __builtin_amdgcn_mfma_f32_16x16x32_bf16(ax0, w0f2, d1, 0, 0, 0);
#pragma unroll
                for (int r = 0; r < 4; ++r) {
                    float v = d0[r];
                    h1g[aq * 4 + r][n] = f2bf(v > 0.f ? v : 0.f);
                }
                if (n == 0) {
#pragma unroll
                    for (int r = 0; r < 4; ++r) {
                        float v = (i < 16) ? (d1[r] > 0.f ? d1[r] : 0.f) : 0.f;
                        h1g[aq * 4 + r][16] = f2bf(v);
                    }
                }
                if (i + 1 < 63 && ((i + 1) >> 3) == wv) {   // next group still ours: prefetch
                    const long gb = i + 1;
                    w0f0 = *(const bf16x8*)&W0f[((gb * 4 + 0) * 64 + lane) * 8];
                    w0f1 = *(const bf16x8*)&W0f[((gb * 4 + 1) * 64 + lane) * 8];
                    w0f2 = *(const bf16x8*)&W0f[((gb * 4 + 2) * 64 + lane) * 8];
                }
            }
        }
        BAR();   // h1g / xhist / xLs visible
    };

#pragma unroll 1
    for (int i = 0; i < 64; i += 2) {
        body(i, w1fE, w2fE);
        body(i + 1, w1fO, w2fO);
    }

    // ldj: publisher lanes are even n; xor-reduce over even lanes, then across waves
#pragma unroll
    for (int r = 0; r < 4; ++r) {
        float v = ldjacc[r];
        v += __shfl_xor(v, 2);
        v += __shfl_xor(v, 4);
        v += __shfl_xor(v, 8);
        if (n == 0) ldjpart[wv][aq * 4 + r] = v;
    }
    BAR();

    if (t < 256) {
        int r = t >> 4, c = (t & 15) * 4;
        float4 v;
        v.x = xLs[r][c]; v.y = xLs[r][c + 1]; v.z = xLs[r][c + 2]; v.w = xLs[r][c + 3];
        *(float4*)&out[(long)(rowbase + r) * 64 + c] = v;
    }
    if (t < 16) {
        float s = 0.f;
#pragma unroll
        for (int w = 0; w < 8; ++w) s += ldjpart[w][t];
        out[(long)BATCH * 64 + rowbase + t] = s;
    }
}

extern "C" void kernel_launch(void* const* d_in, const int* in_sizes, int n_in,
                              void* d_out, int out_size, void* d_ws, size_t ws_size,
                              hipStream_t stream) {
    (void)in_sizes; (void)n_in; (void)out_size; (void)ws_size;
    const float* u  = (const float*)d_in[0];
    const float* W0 = (const float*)d_in[1];
    const float* b0 = (const float*)d_in[2];
    const float* W1 = (const float*)d_in[3];
    const float* b1 = (const float*)d_in[4];
    const float* W2 = (const float*)d_in[5];
    const float* b2 = (const float*)d_in[6];
    float* out = (float*)d_out;

    // d_ws layout (bytes): W1f 4,128,768 | W2f 516,096 | W0f 258,048 | b1p 4,096
    short* W1f = (short*)d_ws;
    short* W2f = (short*)((char*)d_ws + 4128768);
    short* W0f = (short*)((char*)d_ws + 4128768 + 516096);
    float* b1p = (float*)((char*)d_ws + 4128768 + 516096 + 258048);

    prep7<<<dim3(305), dim3(512), 0, stream>>>(W0, b0, W1, b1, W2, W1f, W2f, W0f, b1p);
    made6<<<dim3(BATCH / 16), dim3(NTHR), 0, stream>>>(u, b2, W1f, W2f, W0f, b1p, out);
}